// Round 2
// baseline (3704.169 us; speedup 1.0000x reference)
//
#include <hip/hip_runtime.h>
#include <hip/hip_bf16.h>
#include <math.h>

#define NN 8192
#define EE 131072
#define HH 256
#define LL 3
#define RR 128
#define NGG 64
#define ECH 16384            // edge chunk
#define NCHUNK (EE / ECH)    // 8

__device__ __forceinline__ float silu(float v) { return v / (1.0f + expf(-v)); }

constexpr float kInvSqrt2 = 0.70710678118654752440f;
constexpr float kInvSqrt3 = 0.57735026918962576451f;
constexpr float kInvSqrtH = 0.0625f; // 1/sqrt(256)

// ---------------- utility: zero / copy (float4-granular) ----------------
__global__ void k_zero(float* __restrict__ p, int n4) {
    int i = blockIdx.x * 256 + threadIdx.x;
    if (i < n4) ((float4*)p)[i] = make_float4(0.f, 0.f, 0.f, 0.f);
}
__global__ void k_copy(float* __restrict__ dst, const float* __restrict__ src, int n4) {
    int i = blockIdx.x * 256 + threadIdx.x;
    if (i < n4) ((float4*)dst)[i] = ((const float4*)src)[i];
}

// ---------------- init x = atom_emb[z] ----------------
__global__ void k_init_x(const float* __restrict__ emb, const int* __restrict__ z,
                         float* __restrict__ x) {
    int i = blockIdx.x * 256 + threadIdx.x;      // N*H threads
    int n = i >> 8, c = i & 255;
    x[i] = emb[z[n] * HH + c];
}

// ---------------- edge geometry: unit vector + dist ----------------
__global__ void k_edge_geom(const float* __restrict__ pos, const int* __restrict__ ei,
                            float* __restrict__ ev /*[E,4]*/) {
    int e = blockIdx.x * 256 + threadIdx.x;
    if (e >= EE) return;
    int s = ei[e], d = ei[EE + e];
    float rx = pos[s * 3 + 0] - pos[d * 3 + 0];
    float ry = pos[s * 3 + 1] - pos[d * 3 + 1];
    float rz = pos[s * 3 + 2] - pos[d * 3 + 2];
    float dist = sqrtf(rx * rx + ry * ry + rz * rz);
    float inv = 1.0f / dist;
    ev[e * 4 + 0] = rx * inv;
    ev[e * 4 + 1] = ry * inv;
    ev[e * 4 + 2] = rz * inv;
    ev[e * 4 + 3] = dist;
}

// ---------------- gaussian RBF for one edge chunk ----------------
__global__ void k_rbf(const float* __restrict__ ev, float* __restrict__ rbfc, int base) {
    int le = blockIdx.x;              // local edge in chunk
    int r = threadIdx.x;              // 128 threads
    float d = ev[(base + le) * 4 + 3];
    const float step = 12.0f / 127.0f;
    const float coeff = -0.5f / (step * step);
    float t = d - r * step;
    rbfc[(size_t)le * RR + r] = expf(coeff * t * t);
}

// ---------------- LayerNorm (one row per block, 256 threads = 4 waves) ----------------
__global__ void k_ln(const float* __restrict__ x, const float* __restrict__ w,
                     const float* __restrict__ b, float* __restrict__ out) {
    int n = blockIdx.x, t = threadIdx.x;
    float v = x[(size_t)n * HH + t];
    float s = v, q = v * v;
#pragma unroll
    for (int m = 32; m >= 1; m >>= 1) {
        s += __shfl_xor(s, m, 64);
        q += __shfl_xor(q, m, 64);
    }
    __shared__ float s_sum[4], s_sq[4];
    int wid = t >> 6;
    if ((t & 63) == 0) { s_sum[wid] = s; s_sq[wid] = q; }
    __syncthreads();
    float S = s_sum[0] + s_sum[1] + s_sum[2] + s_sum[3];
    float Q = s_sq[0] + s_sq[1] + s_sq[2] + s_sq[3];
    float mu = S * (1.0f / HH);
    float var = Q * (1.0f / HH) - mu * mu;
    float rs = rsqrtf(var + 1e-5f);
    out[(size_t)n * HH + t] = (v - mu) * rs * w[t] + b[t];
}

// ---------------- generic fp32 tiled GEMM: C = act(A[M,K]@B[K,N] + bias) ----------------
// 64x64 tile, 256 threads, each thread 4x4. M%64==0, N%64==0, K%16==0.
template <int ACT>
__global__ void k_gemm(const float* __restrict__ A, const float* __restrict__ B,
                       const float* __restrict__ bias, float* __restrict__ C,
                       int M, int K, int Nc) {
    __shared__ float As[16][64];
    __shared__ float Bs[16][64];
    int tid = threadIdx.x;
    int bn = blockIdx.x * 64;
    int bm = blockIdx.y * 64;
    int tm = tid >> 4, tn = tid & 15;
    int ar = tid >> 2, ac = (tid & 3) << 2;
    int br = tid >> 4, bc = (tid & 15) << 2;
    float acc[4][4] = {};
    for (int k0 = 0; k0 < K; k0 += 16) {
        float4 av = *(const float4*)&A[(size_t)(bm + ar) * K + k0 + ac];
        As[ac + 0][ar] = av.x;
        As[ac + 1][ar] = av.y;
        As[ac + 2][ar] = av.z;
        As[ac + 3][ar] = av.w;
        float4 bv = *(const float4*)&B[(size_t)(k0 + br) * Nc + bn + bc];
        *(float4*)&Bs[br][bc] = bv;
        __syncthreads();
#pragma unroll
        for (int k = 0; k < 16; ++k) {
            float4 a4 = *(const float4*)&As[k][tm << 2];
            float4 b4 = *(const float4*)&Bs[k][tn << 2];
            float av_[4] = {a4.x, a4.y, a4.z, a4.w};
            float bv_[4] = {b4.x, b4.y, b4.z, b4.w};
#pragma unroll
            for (int i = 0; i < 4; ++i)
#pragma unroll
                for (int j = 0; j < 4; ++j) acc[i][j] += av_[i] * bv_[j];
        }
        __syncthreads();
    }
#pragma unroll
    for (int i = 0; i < 4; ++i) {
        int m = bm + (tm << 2) + i;
#pragma unroll
        for (int j = 0; j < 4; ++j) {
            int n = bn + (tn << 2) + j;
            float v = acc[i][j];
            if (bias) v += bias[n];
            if (ACT == 1) v = silu(v);
            C[(size_t)m * Nc + n] = v;
        }
    }
}

// ---------------- message pass for one edge chunk: atomic scatter ----------------
__global__ void k_message(const float* __restrict__ xh, const float* __restrict__ rbfh,
                          const float* __restrict__ vin, const float* __restrict__ ev,
                          const int* __restrict__ ei, float* __restrict__ dx,
                          float* __restrict__ vout, int base) {
    int le = blockIdx.x;
    int e = base + le;
    int c = threadIdx.x;          // 256 threads
    int s = ei[e], d = ei[EE + e];
    const float* xhs = xh + (size_t)s * 768;
    const float* rb = rbfh + (size_t)le * 768;
    float m0 = xhs[c] * rb[c];
    float m1 = xhs[c + 256] * rb[c + 256] * kInvSqrt3;
    float m2 = xhs[c + 512] * rb[c + 512];
    atomicAdd(&dx[(size_t)d * 256 + c], m0);
    float evx = ev[e * 4 + 0], evy = ev[e * 4 + 1], evz = ev[e * 4 + 2];
    const float* vs = vin + (size_t)s * 768;
    atomicAdd(&vout[(size_t)d * 768 + c], (vs[c] * m1 + m2 * evx) * kInvSqrtH);
    atomicAdd(&vout[(size_t)d * 768 + 256 + c], (vs[c + 256] * m1 + m2 * evy) * kInvSqrtH);
    atomicAdd(&vout[(size_t)d * 768 + 512 + c], (vs[c + 512] * m1 + m2 * evz) * kInvSqrtH);
}

// ---------------- x = (x + dx) * 1/sqrt(2) ----------------
__global__ void k_xupdate(float* __restrict__ x, const float* __restrict__ dx) {
    int i = blockIdx.x * 256 + threadIdx.x;
    x[i] = (x[i] + dx[i]) * kInvSqrt2;
}

// ---------------- vec_dot + hcat = [x, vnorm] ----------------
__global__ void k_vecdot(const float* __restrict__ vp, const float* __restrict__ x,
                         float* __restrict__ vec_dot, float* __restrict__ hcat) {
    int i = blockIdx.x * 256 + threadIdx.x;  // N*H
    int n = i >> 8, c = i & 255;
    const float* p = vp + (size_t)n * 1536;
    float dsum = 0.f, qsum = 0.f;
#pragma unroll
    for (int k = 0; k < 3; ++k) {
        float v1 = p[k * 512 + c];
        float v2 = p[k * 512 + 256 + c];
        dsum += v1 * v2;
        qsum += v2 * v2;
    }
    vec_dot[i] = dsum * kInvSqrtH;
    hcat[(size_t)n * 512 + c] = x[i];
    hcat[(size_t)n * 512 + 256 + c] = sqrtf(qsum + 1e-8f);
}

// ---------------- update epilogue ----------------
__global__ void k_update_out(const float* __restrict__ hout, const float* __restrict__ vec_dot,
                             const float* __restrict__ vp, float* __restrict__ x,
                             float* __restrict__ vout) {
    int i = blockIdx.x * 256 + threadIdx.x;  // N*H
    int n = i >> 8, c = i & 255;
    float xv1 = hout[(size_t)n * 768 + c];
    float xv2 = hout[(size_t)n * 768 + 256 + c];
    float xv3 = hout[(size_t)n * 768 + 512 + c];
    float dxv = (xv1 + xv2 * vec_dot[i]) * kInvSqrt2;
    x[i] = (x[i] + dxv) * kInvSqrt2;
#pragma unroll
    for (int k = 0; k < 3; ++k)
        vout[(size_t)n * 768 + k * 256 + c] += xv3 * vp[(size_t)n * 1536 + k * 512 + c];
}

// ---------------- energy head ----------------
__global__ void k_energy(const float* __restrict__ x, const float* __restrict__ w1,
                         const float* __restrict__ b1, const float* __restrict__ w2,
                         const float* __restrict__ b2, const int* __restrict__ batch,
                         float* __restrict__ out) {
    int n = blockIdx.x;
    int j = threadIdx.x;          // 128 threads = 2 waves
    const float* xr = x + (size_t)n * 256;
    float acc = 0.f;
#pragma unroll 4
    for (int i = 0; i < 256; ++i) acc += xr[i] * w1[i * 128 + j];
    acc += b1[j];
    float val = silu(acc) * w2[j];
#pragma unroll
    for (int m = 32; m >= 1; m >>= 1) val += __shfl_xor(val, m, 64);
    __shared__ float part[2];
    if ((j & 63) == 0) part[j >> 6] = val;
    __syncthreads();
    if (j == 0) atomicAdd(&out[batch[n]], part[0] + part[1] + b2[0]);
}

extern "C" void kernel_launch(void* const* d_in, const int* in_sizes, int n_in,
                              void* d_out, int out_size, void* d_ws, size_t ws_size,
                              hipStream_t stream) {
    const float* pos      = (const float*)d_in[0];
    const float* atom_emb = (const float*)d_in[1];
    const float* ln_w     = (const float*)d_in[2];
    const float* ln_b     = (const float*)d_in[3];
    const float* xp_w1    = (const float*)d_in[4];
    const float* xp_b1    = (const float*)d_in[5];
    const float* xp_w2    = (const float*)d_in[6];
    const float* xp_b2    = (const float*)d_in[7];
    const float* rbf_w    = (const float*)d_in[8];
    const float* rbf_b    = (const float*)d_in[9];
    const float* vec_w    = (const float*)d_in[10];
    const float* xv_w1    = (const float*)d_in[11];
    const float* xv_b1    = (const float*)d_in[12];
    const float* xv_w2    = (const float*)d_in[13];
    const float* xv_b2    = (const float*)d_in[14];
    const float* oe_w1    = (const float*)d_in[15];
    const float* oe_b1    = (const float*)d_in[16];
    const float* oe_w2    = (const float*)d_in[17];
    const float* oe_b2    = (const float*)d_in[18];
    const int*   z        = (const int*)d_in[19];
    const int*   ei       = (const int*)d_in[20];
    const int*   batch    = (const int*)d_in[21];
    float* out = (float*)d_out;

    // ---- lean workspace plan (~186 MB total; aliased live ranges) ----
    char* ws = (char*)d_ws;
    size_t off = 0;
    auto alloc = [&](size_t b) {
        void* p = ws + off;
        off = (off + b + 255) & ~(size_t)255;
        return p;
    };
    float* ev     = (float*)alloc((size_t)EE * 4 * 4);        //   2 MB
    float* x      = (float*)alloc((size_t)NN * HH * 4);       //   8 MB
    float* vecA   = (float*)alloc((size_t)NN * 768 * 4);      //  24 MB
    float* vecB   = (float*)alloc((size_t)NN * 768 * 4);      //  24 MB
    float* xln    = (float*)alloc((size_t)NN * HH * 4);       //   8 MB
    float* t1     = (float*)alloc((size_t)NN * HH * 4);       //   8 MB  (also h1)
    float* xh     = (float*)alloc((size_t)NN * 768 * 4);      //  24 MB  (also hout)
    float* dx     = (float*)alloc((size_t)NN * HH * 4);       //   8 MB
    float* vdot   = (float*)alloc((size_t)NN * HH * 4);       //   8 MB
    float* hcat   = (float*)alloc((size_t)NN * 512 * 4);      //  16 MB
    float* rbfc   = (float*)alloc((size_t)ECH * RR * 4);      //   8 MB
    float* big    = (float*)alloc((size_t)NN * 1536 * 4);     //  48 MB  (vp | rbfh_chunk)
    (void)ws_size;
    float* vp    = big;   // [N,1536], update phase
    float* rbfhc = big;   // [ECH,768] = 48 MB, message phase (disjoint live range)
    float* h1   = t1;
    float* hout = xh;

    const int NH4  = NN * HH / 4;    // float4 count for [N,H]
    const int NV4  = NN * 768 / 4;   // float4 count for [N,3,H]

    k_zero<<<(NV4 + 255) / 256, 256, 0, stream>>>(vecA, NV4);
    k_init_x<<<NN, 256, 0, stream>>>(atom_emb, z, x);
    k_edge_geom<<<EE / 256, 256, 0, stream>>>(pos, ei, ev);

    float* vin = vecA;
    float* vout = vecB;
    for (int l = 0; l < LL; ++l) {
        // ---- PaiNNMessage ----
        k_ln<<<NN, 256, 0, stream>>>(x, ln_w + l * HH, ln_b + l * HH, xln);
        k_gemm<1><<<dim3(HH / 64, NN / 64), 256, 0, stream>>>(
            xln, xp_w1 + (size_t)l * HH * HH, xp_b1 + l * HH, t1, NN, HH, HH);
        k_gemm<0><<<dim3(768 / 64, NN / 64), 256, 0, stream>>>(
            t1, xp_w2 + (size_t)l * HH * 768, xp_b2 + l * 768, xh, NN, HH, 768);
        k_zero<<<(NH4 + 255) / 256, 256, 0, stream>>>(dx, NH4);
        k_copy<<<(NV4 + 255) / 256, 256, 0, stream>>>(vout, vin, NV4);
        for (int c0 = 0; c0 < NCHUNK; ++c0) {
            int base = c0 * ECH;
            k_rbf<<<ECH, RR, 0, stream>>>(ev, rbfc, base);
            k_gemm<0><<<dim3(768 / 64, ECH / 64), 256, 0, stream>>>(
                rbfc, rbf_w + (size_t)l * RR * 768, rbf_b + l * 768, rbfhc, ECH, RR, 768);
            k_message<<<ECH, 256, 0, stream>>>(xh, rbfhc, vin, ev, ei, dx, vout, base);
        }
        k_xupdate<<<NN, 256, 0, stream>>>(x, dx);

        // ---- PaiNNUpdate ----
        k_gemm<0><<<dim3(512 / 64, 3 * NN / 64), 256, 0, stream>>>(
            vout, vec_w + (size_t)l * HH * 512, nullptr, vp, 3 * NN, HH, 512);
        k_vecdot<<<NN, 256, 0, stream>>>(vp, x, vdot, hcat);
        k_gemm<1><<<dim3(HH / 64, NN / 64), 256, 0, stream>>>(
            hcat, xv_w1 + (size_t)l * 512 * HH, xv_b1 + l * HH, h1, NN, 512, HH);
        k_gemm<0><<<dim3(768 / 64, NN / 64), 256, 0, stream>>>(
            h1, xv_w2 + (size_t)l * HH * 768, xv_b2 + l * 768, hout, NN, HH, 768);
        k_update_out<<<NN, 256, 0, stream>>>(hout, vdot, vp, x, vout);

        float* tmp = vin; vin = vout; vout = tmp;
    }

    k_zero<<<1, 256, 0, stream>>>(out, NGG / 4);
    k_energy<<<NN, 128, 0, stream>>>(x, oe_w1, oe_b1, oe_w2, oe_b2, batch, out);
}

// Round 3
// 2337.577 us; speedup vs baseline: 1.5846x; 1.5846x over previous
//
#include <hip/hip_runtime.h>
#include <hip/hip_bf16.h>
#include <math.h>

#define NN 8192
#define EE 131072
#define HH 256
#define LL 3
#define RR 128
#define NGG 64
#define ECH 32768            // edge chunk
#define NCHUNK (EE / ECH)    // 4

typedef __attribute__((ext_vector_type(8))) short bf16x8;
typedef __attribute__((ext_vector_type(4))) float f32x4;

__device__ __forceinline__ float silu(float v) { return v / (1.0f + expf(-v)); }
__device__ __forceinline__ float b2f(unsigned short u) { return __uint_as_float(((unsigned)u) << 16); }
__device__ __forceinline__ unsigned short f2b(float f) {
    unsigned u = __float_as_uint(f);
    u += 0x7fff + ((u >> 16) & 1);
    return (unsigned short)(u >> 16);
}

constexpr float kInvSqrt2 = 0.70710678118654752440f;
constexpr float kInvSqrt3 = 0.57735026918962576451f;
constexpr float kInvSqrtH = 0.0625f; // 1/sqrt(256)

// ---------------- utility: zero / copy / fp32->bf16 (float4-granular) ----------------
__global__ void k_zero(float* __restrict__ p, int n4) {
    int i = blockIdx.x * 256 + threadIdx.x;
    if (i < n4) ((float4*)p)[i] = make_float4(0.f, 0.f, 0.f, 0.f);
}
__global__ void k_copy(float* __restrict__ dst, const float* __restrict__ src, int n4) {
    int i = blockIdx.x * 256 + threadIdx.x;
    if (i < n4) ((float4*)dst)[i] = ((const float4*)src)[i];
}
__global__ void k_b16(unsigned short* __restrict__ o, const float* __restrict__ in, int n4) {
    int i = blockIdx.x * 256 + threadIdx.x;
    if (i >= n4) return;
    float4 v = ((const float4*)in)[i];
    ushort4 u;
    u.x = f2b(v.x); u.y = f2b(v.y); u.z = f2b(v.z); u.w = f2b(v.w);
    ((ushort4*)o)[i] = u;
}

// ---------------- weight transpose: in[K,N] fp32 -> out[N,K] bf16 (K,N mult of 32) ----
__global__ void k_wt(const float* __restrict__ in, unsigned short* __restrict__ out,
                     int K, int N) {
    __shared__ float tile[32][33];
    int bn = blockIdx.x * 32, bk = blockIdx.y * 32;
    int tx = threadIdx.x & 31, ty = threadIdx.x >> 5;   // 32 x 8
#pragma unroll
    for (int i = 0; i < 32; i += 8)
        tile[ty + i][tx] = in[(size_t)(bk + ty + i) * N + bn + tx];
    __syncthreads();
#pragma unroll
    for (int i = 0; i < 32; i += 8)
        out[(size_t)(bn + ty + i) * K + bk + tx] = f2b(tile[tx][ty + i]);
}

// ---------------- init x = atom_emb[z] ----------------
__global__ void k_init_x(const float* __restrict__ emb, const int* __restrict__ z,
                         float* __restrict__ x) {
    int i = blockIdx.x * 256 + threadIdx.x;
    int n = i >> 8, c = i & 255;
    x[i] = emb[z[n] * HH + c];
}

// ---------------- edge geometry ----------------
__global__ void k_edge_geom(const float* __restrict__ pos, const int* __restrict__ ei,
                            float* __restrict__ ev /*[E,4]*/) {
    int e = blockIdx.x * 256 + threadIdx.x;
    if (e >= EE) return;
    int s = ei[e], d = ei[EE + e];
    float rx = pos[s * 3 + 0] - pos[d * 3 + 0];
    float ry = pos[s * 3 + 1] - pos[d * 3 + 1];
    float rz = pos[s * 3 + 2] - pos[d * 3 + 2];
    float dist = sqrtf(rx * rx + ry * ry + rz * rz);
    float inv = 1.0f / dist;
    ev[e * 4 + 0] = rx * inv;
    ev[e * 4 + 1] = ry * inv;
    ev[e * 4 + 2] = rz * inv;
    ev[e * 4 + 3] = dist;
}

// ---------------- gaussian RBF for one edge chunk (bf16 out) ----------------
__global__ void k_rbf(const float* __restrict__ ev, unsigned short* __restrict__ rbfc,
                      int base) {
    int le = blockIdx.x;
    int r = threadIdx.x;              // 128 threads
    float d = ev[(base + le) * 4 + 3];
    const float step = 12.0f / 127.0f;
    const float coeff = -0.5f / (step * step);
    float t = d - r * step;
    rbfc[(size_t)le * RR + r] = f2b(expf(coeff * t * t));
}

// ---------------- LayerNorm -> bf16 ----------------
__global__ void k_ln(const float* __restrict__ x, const float* __restrict__ w,
                     const float* __restrict__ b, unsigned short* __restrict__ out) {
    int n = blockIdx.x, t = threadIdx.x;
    float v = x[(size_t)n * HH + t];
    float s = v, q = v * v;
#pragma unroll
    for (int m = 32; m >= 1; m >>= 1) {
        s += __shfl_xor(s, m, 64);
        q += __shfl_xor(q, m, 64);
    }
    __shared__ float s_sum[4], s_sq[4];
    int wid = t >> 6;
    if ((t & 63) == 0) { s_sum[wid] = s; s_sq[wid] = q; }
    __syncthreads();
    float S = s_sum[0] + s_sum[1] + s_sum[2] + s_sum[3];
    float Q = s_sq[0] + s_sq[1] + s_sq[2] + s_sq[3];
    float mu = S * (1.0f / HH);
    float var = Q * (1.0f / HH) - mu * mu;
    float rs = rsqrtf(var + 1e-5f);
    out[(size_t)n * HH + t] = f2b((v - mu) * rs * w[t] + b[t]);
}

// ---------------- bf16 MFMA GEMM: C = act(A[M,K] @ BT[N,K]^T + bias) ----------------
// 128x128 tile, 256 threads = 4 waves (2x2), each wave 64x64 via 4x4 MFMA 16x16x32.
// M%128==0, N%128==0, K%32==0. A,BT bf16 row-major. C fp32 or bf16.
template <int OUT_BF16, int ACT>
__global__ __launch_bounds__(256) void k_gemm(
    const unsigned short* __restrict__ A, const unsigned short* __restrict__ BT,
    const float* __restrict__ bias, void* __restrict__ C, int M, int K, int N) {
    __shared__ uint4 As4[512];   // [128 rows][32 k] bf16 = 8 KB
    __shared__ uint4 Bs4[512];
    unsigned short* As = (unsigned short*)As4;
    unsigned short* Bs = (unsigned short*)Bs4;
    int tid = threadIdx.x;
    int wave = tid >> 6, lane = tid & 63;
    int bm = blockIdx.y * 128, bn = blockIdx.x * 128;
    int wm = (wave >> 1) * 64, wn = (wave & 1) * 64;
    int lm = lane & 15;          // row (A) / col (B) within 16-tile
    int kg = lane >> 4;          // k-group: k = kg*8 .. +8
    f32x4 acc[4][4] = {};

    for (int k0 = 0; k0 < K; k0 += 32) {
#pragma unroll
        for (int it = 0; it < 2; ++it) {
            int idx = it * 256 + tid;
            int r = idx >> 2, seg = idx & 3;
            As4[idx] = *(const uint4*)&A[(size_t)(bm + r) * K + k0 + seg * 8];
            Bs4[idx] = *(const uint4*)&BT[(size_t)(bn + r) * K + k0 + seg * 8];
        }
        __syncthreads();
        bf16x8 af[4], bfr[4];
#pragma unroll
        for (int i = 0; i < 4; ++i)
            af[i] = *(const bf16x8*)&As[(wm + i * 16 + lm) * 32 + kg * 8];
#pragma unroll
        for (int j = 0; j < 4; ++j)
            bfr[j] = *(const bf16x8*)&Bs[(wn + j * 16 + lm) * 32 + kg * 8];
#pragma unroll
        for (int i = 0; i < 4; ++i)
#pragma unroll
            for (int j = 0; j < 4; ++j)
                acc[i][j] = __builtin_amdgcn_mfma_f32_16x16x32_bf16(af[i], bfr[j], acc[i][j], 0, 0, 0);
        __syncthreads();
    }

    // epilogue: C/D layout col=lane&15, row=(lane>>4)*4+reg
#pragma unroll
    for (int j = 0; j < 4; ++j) {
        int col = bn + wn + j * 16 + lm;
        float bv = bias ? bias[col] : 0.f;
#pragma unroll
        for (int i = 0; i < 4; ++i) {
            int row0 = bm + wm + i * 16 + kg * 4;
#pragma unroll
            for (int r = 0; r < 4; ++r) {
                float v = acc[i][j][r] + bv;
                if (ACT) v = silu(v);
                if (OUT_BF16)
                    ((unsigned short*)C)[(size_t)(row0 + r) * N + col] = f2b(v);
                else
                    ((float*)C)[(size_t)(row0 + r) * N + col] = v;
            }
        }
    }
}

// ---------------- message pass for one edge chunk: atomic scatter ----------------
__global__ void k_message(const float* __restrict__ xh, const unsigned short* __restrict__ rbfh,
                          const float* __restrict__ vin, const float* __restrict__ ev,
                          const int* __restrict__ ei, float* __restrict__ dx,
                          float* __restrict__ vout, int base) {
    int le = blockIdx.x;
    int e = base + le;
    int c = threadIdx.x;          // 256 threads
    int s = ei[e], d = ei[EE + e];
    const float* xhs = xh + (size_t)s * 768;
    const unsigned short* rb = rbfh + (size_t)le * 768;
    float m0 = xhs[c] * b2f(rb[c]);
    float m1 = xhs[c + 256] * b2f(rb[c + 256]) * kInvSqrt3;
    float m2 = xhs[c + 512] * b2f(rb[c + 512]);
    atomicAdd(&dx[(size_t)d * 256 + c], m0);
    float evx = ev[e * 4 + 0], evy = ev[e * 4 + 1], evz = ev[e * 4 + 2];
    const float* vs = vin + (size_t)s * 768;
    atomicAdd(&vout[(size_t)d * 768 + c], (vs[c] * m1 + m2 * evx) * kInvSqrtH);
    atomicAdd(&vout[(size_t)d * 768 + 256 + c], (vs[c + 256] * m1 + m2 * evy) * kInvSqrtH);
    atomicAdd(&vout[(size_t)d * 768 + 512 + c], (vs[c + 512] * m1 + m2 * evz) * kInvSqrtH);
}

// ---------------- x = (x + dx) * 1/sqrt(2) ----------------
__global__ void k_xupdate(float* __restrict__ x, const float* __restrict__ dx) {
    int i = blockIdx.x * 256 + threadIdx.x;
    x[i] = (x[i] + dx[i]) * kInvSqrt2;
}

// ---------------- vec_dot + hcat(bf16) = [x, vnorm] ----------------
__global__ void k_vecdot(const float* __restrict__ vp, const float* __restrict__ x,
                         float* __restrict__ vec_dot, unsigned short* __restrict__ hcat) {
    int i = blockIdx.x * 256 + threadIdx.x;  // N*H
    int n = i >> 8, c = i & 255;
    const float* p = vp + (size_t)n * 1536;
    float dsum = 0.f, qsum = 0.f;
#pragma unroll
    for (int k = 0; k < 3; ++k) {
        float v1 = p[k * 512 + c];
        float v2 = p[k * 512 + 256 + c];
        dsum += v1 * v2;
        qsum += v2 * v2;
    }
    vec_dot[i] = dsum * kInvSqrtH;
    hcat[(size_t)n * 512 + c] = f2b(x[i]);
    hcat[(size_t)n * 512 + 256 + c] = f2b(sqrtf(qsum + 1e-8f));
}

// ---------------- update epilogue ----------------
__global__ void k_update_out(const float* __restrict__ hout, const float* __restrict__ vec_dot,
                             const float* __restrict__ vp, float* __restrict__ x,
                             float* __restrict__ vout) {
    int i = blockIdx.x * 256 + threadIdx.x;  // N*H
    int n = i >> 8, c = i & 255;
    float xv1 = hout[(size_t)n * 768 + c];
    float xv2 = hout[(size_t)n * 768 + 256 + c];
    float xv3 = hout[(size_t)n * 768 + 512 + c];
    float dxv = (xv1 + xv2 * vec_dot[i]) * kInvSqrt2;
    x[i] = (x[i] + dxv) * kInvSqrt2;
#pragma unroll
    for (int k = 0; k < 3; ++k)
        vout[(size_t)n * 768 + k * 256 + c] += xv3 * vp[(size_t)n * 1536 + k * 512 + c];
}

// ---------------- energy reduce: per-atom dot + segment sum ----------------
__global__ void k_energy2(const float* __restrict__ h, const float* __restrict__ w2,
                          const float* __restrict__ b2, const int* __restrict__ batch,
                          float* __restrict__ out) {
    int n = blockIdx.x, j = threadIdx.x;   // 128 threads
    float v = h[(size_t)n * 128 + j] * w2[j];
#pragma unroll
    for (int m = 32; m >= 1; m >>= 1) v += __shfl_xor(v, m, 64);
    __shared__ float p[2];
    if ((j & 63) == 0) p[j >> 6] = v;
    __syncthreads();
    if (j == 0) atomicAdd(&out[batch[n]], p[0] + p[1] + b2[0]);
}

extern "C" void kernel_launch(void* const* d_in, const int* in_sizes, int n_in,
                              void* d_out, int out_size, void* d_ws, size_t ws_size,
                              hipStream_t stream) {
    const float* pos      = (const float*)d_in[0];
    const float* atom_emb = (const float*)d_in[1];
    const float* ln_w     = (const float*)d_in[2];
    const float* ln_b     = (const float*)d_in[3];
    const float* xp_w1    = (const float*)d_in[4];
    const float* xp_b1    = (const float*)d_in[5];
    const float* xp_w2    = (const float*)d_in[6];
    const float* xp_b2    = (const float*)d_in[7];
    const float* rbf_w    = (const float*)d_in[8];
    const float* rbf_b    = (const float*)d_in[9];
    const float* vec_w    = (const float*)d_in[10];
    const float* xv_w1    = (const float*)d_in[11];
    const float* xv_b1    = (const float*)d_in[12];
    const float* xv_w2    = (const float*)d_in[13];
    const float* xv_b2    = (const float*)d_in[14];
    const float* oe_w1    = (const float*)d_in[15];
    const float* oe_b1    = (const float*)d_in[16];
    const float* oe_w2    = (const float*)d_in[17];
    const float* oe_b2    = (const float*)d_in[18];
    const int*   z        = (const int*)d_in[19];
    const int*   ei       = (const int*)d_in[20];
    const int*   batch    = (const int*)d_in[21];
    float* out = (float*)d_out;

    typedef unsigned short u16;
    char* ws = (char*)d_ws;
    size_t off = 0;
    auto alloc = [&](size_t b) {
        void* p = ws + off;
        off = (off + b + 255) & ~(size_t)255;
        return p;
    };
    float* ev     = (float*)alloc((size_t)EE * 4 * 4);        //   2 MB
    float* x      = (float*)alloc((size_t)NN * HH * 4);       //   8 MB
    float* vecA   = (float*)alloc((size_t)NN * 768 * 4);      //  24 MB
    float* vecB   = (float*)alloc((size_t)NN * 768 * 4);      //  24 MB
    float* xh     = (float*)alloc((size_t)NN * 768 * 4);      //  24 MB (alias hout)
    float* dx     = (float*)alloc((size_t)NN * HH * 4);       //   8 MB
    float* scr8   = (float*)alloc((size_t)ECH * RR * 2);      //   8 MB (vdot | rbfcb | heng)
    u16*   hcatb  = (u16*)alloc((size_t)NN * 512 * 2);        //   8 MB
    u16*   xlnb   = (u16*)alloc((size_t)NN * HH * 2);         //   4 MB (alias xb)
    u16*   t1b    = (u16*)alloc((size_t)NN * HH * 2);         //   4 MB
    u16*   h1b    = (u16*)alloc((size_t)NN * HH * 2);         //   4 MB
    u16*   voutb  = (u16*)alloc((size_t)3 * NN * HH * 2);     //  12 MB
    float* big    = (float*)alloc((size_t)NN * 1536 * 4);     //  48 MB (vp | rbfhc)
    // transposed bf16 weights
    u16* xp_w1T = (u16*)alloc((size_t)3 * 256 * 256 * 2);
    u16* xp_w2T = (u16*)alloc((size_t)3 * 768 * 256 * 2);
    u16* rbf_wT = (u16*)alloc((size_t)3 * 768 * 128 * 2);
    u16* vec_wT = (u16*)alloc((size_t)3 * 512 * 256 * 2);
    u16* xv_w1T = (u16*)alloc((size_t)3 * 256 * 512 * 2);
    u16* xv_w2T = (u16*)alloc((size_t)3 * 768 * 256 * 2);
    u16* oe_w1T = (u16*)alloc((size_t)128 * 256 * 2);
    (void)ws_size;

    float* vp    = big;            // [N,1536] fp32, update phase
    u16*   rbfhc = (u16*)big;      // [ECH,768] bf16, message phase
    float* vdot  = scr8;           // update phase
    u16*   rbfcb = (u16*)scr8;     // message phase
    float* heng  = scr8;           // energy phase
    float* hout  = xh;
    u16*   xb    = xlnb;

    const int NH4 = NN * HH / 4;
    const int NV4 = NN * 768 / 4;

    // weight transposes (bf16, [N,K] from [K,N])
    for (int l = 0; l < LL; ++l) {
        k_wt<<<dim3(256 / 32, 256 / 32), 256, 0, stream>>>(xp_w1 + (size_t)l * 256 * 256, xp_w1T + (size_t)l * 256 * 256, 256, 256);
        k_wt<<<dim3(768 / 32, 256 / 32), 256, 0, stream>>>(xp_w2 + (size_t)l * 256 * 768, xp_w2T + (size_t)l * 768 * 256, 256, 768);
        k_wt<<<dim3(768 / 32, 128 / 32), 256, 0, stream>>>(rbf_w + (size_t)l * 128 * 768, rbf_wT + (size_t)l * 768 * 128, 128, 768);
        k_wt<<<dim3(512 / 32, 256 / 32), 256, 0, stream>>>(vec_w + (size_t)l * 256 * 512, vec_wT + (size_t)l * 512 * 256, 256, 512);
        k_wt<<<dim3(256 / 32, 512 / 32), 256, 0, stream>>>(xv_w1 + (size_t)l * 512 * 256, xv_w1T + (size_t)l * 256 * 512, 512, 256);
        k_wt<<<dim3(768 / 32, 256 / 32), 256, 0, stream>>>(xv_w2 + (size_t)l * 256 * 768, xv_w2T + (size_t)l * 768 * 256, 256, 768);
    }
    k_wt<<<dim3(128 / 32, 256 / 32), 256, 0, stream>>>(oe_w1, oe_w1T, 256, 128);

    k_zero<<<(NV4 + 255) / 256, 256, 0, stream>>>(vecA, NV4);
    k_init_x<<<NN, 256, 0, stream>>>(atom_emb, z, x);
    k_edge_geom<<<EE / 256, 256, 0, stream>>>(pos, ei, ev);

    float* vin = vecA;
    float* vout = vecB;
    for (int l = 0; l < LL; ++l) {
        // ---- PaiNNMessage ----
        k_ln<<<NN, 256, 0, stream>>>(x, ln_w + l * HH, ln_b + l * HH, xlnb);
        k_gemm<1, 1><<<dim3(256 / 128, NN / 128), 256, 0, stream>>>(
            xlnb, xp_w1T + (size_t)l * 256 * 256, xp_b1 + l * HH, t1b, NN, 256, 256);
        k_gemm<0, 0><<<dim3(768 / 128, NN / 128), 256, 0, stream>>>(
            t1b, xp_w2T + (size_t)l * 768 * 256, xp_b2 + l * 768, xh, NN, 256, 768);
        k_zero<<<(NH4 + 255) / 256, 256, 0, stream>>>(dx, NH4);
        k_copy<<<(NV4 + 255) / 256, 256, 0, stream>>>(vout, vin, NV4);
        for (int c0 = 0; c0 < NCHUNK; ++c0) {
            int base = c0 * ECH;
            k_rbf<<<ECH, RR, 0, stream>>>(ev, rbfcb, base);
            k_gemm<1, 0><<<dim3(768 / 128, ECH / 128), 256, 0, stream>>>(
                rbfcb, rbf_wT + (size_t)l * 768 * 128, rbf_b + l * 768, rbfhc, ECH, 128, 768);
            k_message<<<ECH, 256, 0, stream>>>(xh, rbfhc, vin, ev, ei, dx, vout, base);
        }
        k_xupdate<<<NN, 256, 0, stream>>>(x, dx);

        // ---- PaiNNUpdate ----
        k_b16<<<((3 * NN * HH / 4) + 255) / 256, 256, 0, stream>>>(voutb, vout, 3 * NN * HH / 4);
        k_gemm<0, 0><<<dim3(512 / 128, 3 * NN / 128), 256, 0, stream>>>(
            voutb, vec_wT + (size_t)l * 512 * 256, nullptr, vp, 3 * NN, 256, 512);
        k_vecdot<<<NN, 256, 0, stream>>>(vp, x, vdot, hcatb);
        k_gemm<1, 1><<<dim3(256 / 128, NN / 128), 256, 0, stream>>>(
            hcatb, xv_w1T + (size_t)l * 256 * 512, xv_b1 + l * HH, h1b, NN, 512, 256);
        k_gemm<0, 0><<<dim3(768 / 128, NN / 128), 256, 0, stream>>>(
            h1b, xv_w2T + (size_t)l * 768 * 256, xv_b2 + l * 768, hout, NN, 256, 768);
        k_update_out<<<NN, 256, 0, stream>>>(hout, vdot, vp, x, vout);

        float* tmp = vin; vin = vout; vout = tmp;
    }

    // ---- energy head ----
    k_b16<<<(NH4 + 255) / 256, 256, 0, stream>>>(xb, x, NH4);
    k_gemm<0, 1><<<dim3(128 / 128, NN / 128), 256, 0, stream>>>(
        xb, oe_w1T, oe_b1, heng, NN, 256, 128);
    k_zero<<<1, 256, 0, stream>>>(out, NGG / 4);
    k_energy2<<<NN, 128, 0, stream>>>(heng, oe_w2, oe_b2, batch, out);
}

// Round 4
// 1415.149 us; speedup vs baseline: 2.6175x; 1.6518x over previous
//
#include <hip/hip_runtime.h>
#include <hip/hip_bf16.h>
#include <math.h>

#define NN 8192
#define EE 131072
#define HH 256
#define LL 3
#define RR 128
#define NGG 64
#define ECH 32768            // edge chunk
#define NCHUNK (EE / ECH)    // 4

typedef __attribute__((ext_vector_type(8))) short bf16x8;
typedef __attribute__((ext_vector_type(4))) float f32x4;
typedef unsigned short u16;

union U4 { ushort4 v; unsigned short a[4]; };

__device__ __forceinline__ float silu(float v) { return v / (1.0f + expf(-v)); }
__device__ __forceinline__ float b2f(unsigned short u) { return __uint_as_float(((unsigned)u) << 16); }
__device__ __forceinline__ unsigned short f2b(float f) {
    unsigned u = __float_as_uint(f);
    u += 0x7fff + ((u >> 16) & 1);
    return (unsigned short)(u >> 16);
}

constexpr float kInvSqrt2 = 0.70710678118654752440f;
constexpr float kInvSqrt3 = 0.57735026918962576451f;
constexpr float kInvSqrtH = 0.0625f; // 1/sqrt(256)

// ---------------- utility ----------------
__global__ void k_zero(float* __restrict__ p, int n4) {
    int i = blockIdx.x * 256 + threadIdx.x;
    if (i < n4) ((float4*)p)[i] = make_float4(0.f, 0.f, 0.f, 0.f);
}
__global__ void k_b16(u16* __restrict__ o, const float* __restrict__ in, int n4) {
    int i = blockIdx.x * 256 + threadIdx.x;
    if (i >= n4) return;
    float4 v = ((const float4*)in)[i];
    ushort4 u;
    u.x = f2b(v.x); u.y = f2b(v.y); u.z = f2b(v.z); u.w = f2b(v.w);
    ((ushort4*)o)[i] = u;
}

// ---------------- weight transpose: in[K,N] fp32 -> out[N,K] bf16 ----------------
__global__ void k_wt(const float* __restrict__ in, u16* __restrict__ out, int K, int N) {
    __shared__ float tile[32][33];
    int bn = blockIdx.x * 32, bk = blockIdx.y * 32;
    int tx = threadIdx.x & 31, ty = threadIdx.x >> 5;   // 32 x 8
#pragma unroll
    for (int i = 0; i < 32; i += 8)
        tile[ty + i][tx] = in[(size_t)(bk + ty + i) * N + bn + tx];
    __syncthreads();
#pragma unroll
    for (int i = 0; i < 32; i += 8)
        out[(size_t)(bn + ty + i) * K + bk + tx] = f2b(tile[tx][ty + i]);
}

// ---------------- init x = atom_emb[z] ----------------
__global__ void k_init_x(const float* __restrict__ emb, const int* __restrict__ z,
                         float* __restrict__ x) {
    int i = blockIdx.x * 256 + threadIdx.x;
    int n = i >> 8, c = i & 255;
    x[i] = emb[z[n] * HH + c];
}

// ---------------- edge geometry ----------------
__global__ void k_edge_geom(const float* __restrict__ pos, const int* __restrict__ ei,
                            float* __restrict__ ev /*[E,4]*/) {
    int e = blockIdx.x * 256 + threadIdx.x;
    if (e >= EE) return;
    int s = ei[e], d = ei[EE + e];
    float rx = pos[s * 3 + 0] - pos[d * 3 + 0];
    float ry = pos[s * 3 + 1] - pos[d * 3 + 1];
    float rz = pos[s * 3 + 2] - pos[d * 3 + 2];
    float dist = sqrtf(rx * rx + ry * ry + rz * rz);
    float inv = 1.0f / dist;
    ((float4*)ev)[e] = make_float4(rx * inv, ry * inv, rz * inv, dist);
}

// ---------------- CSR build ----------------
__global__ void k_hist(const int* __restrict__ ei, int* __restrict__ deg) {
    int e = blockIdx.x * 256 + threadIdx.x;
    if (e < EE) atomicAdd(&deg[ei[EE + e]], 1);
}
__global__ void k_scan(const int* __restrict__ deg, int* __restrict__ row_ptr,
                       int* __restrict__ fill) {
    __shared__ int buf[256];
    __shared__ int carry_s;
    int t = threadIdx.x;
    if (t == 0) carry_s = 0;
    __syncthreads();
    for (int r = 0; r < NN; r += 256) {
        int v = deg[r + t];
        buf[t] = v;
        __syncthreads();
        for (int ofs = 1; ofs < 256; ofs <<= 1) {
            int add = (t >= ofs) ? buf[t - ofs] : 0;
            __syncthreads();
            buf[t] += add;
            __syncthreads();
        }
        int excl = buf[t] - v;
        int carry = carry_s;
        row_ptr[r + t] = carry + excl;
        fill[r + t] = carry + excl;
        __syncthreads();
        if (t == 255) carry_s = carry + buf[t];
        __syncthreads();
    }
    if (t == 0) row_ptr[NN] = carry_s;
}
__global__ void k_scatter(const int* __restrict__ ei, const float* __restrict__ ev,
                          int* __restrict__ fill, int* __restrict__ srcp,
                          float4* __restrict__ evp) {
    int e = blockIdx.x * 256 + threadIdx.x;
    if (e >= EE) return;
    int d = ei[EE + e];
    int pos = atomicAdd(&fill[d], 1);
    srcp[pos] = ei[e];
    evp[pos] = ((const float4*)ev)[e];
}

// ---------------- gaussian RBF for one edge chunk (CSR order, bf16 out) -------------
__global__ void k_rbf(const float4* __restrict__ evp, u16* __restrict__ rbfc, int base) {
    int le = blockIdx.x * 2 + (threadIdx.x >> 7);
    int r = threadIdx.x & 127;
    float d = evp[base + le].w;
    const float step = 12.0f / 127.0f;
    const float coeff = -0.5f / (step * step);
    float t = d - r * step;
    rbfc[(size_t)le * RR + r] = f2b(expf(coeff * t * t));
}

// ---------------- LayerNorm -> bf16 ----------------
__global__ void k_ln(const float* __restrict__ x, const float* __restrict__ w,
                     const float* __restrict__ b, u16* __restrict__ out) {
    int n = blockIdx.x, t = threadIdx.x;
    float v = x[(size_t)n * HH + t];
    float s = v, q = v * v;
#pragma unroll
    for (int m = 32; m >= 1; m >>= 1) {
        s += __shfl_xor(s, m, 64);
        q += __shfl_xor(q, m, 64);
    }
    __shared__ float s_sum[4], s_sq[4];
    int wid = t >> 6;
    if ((t & 63) == 0) { s_sum[wid] = s; s_sq[wid] = q; }
    __syncthreads();
    float S = s_sum[0] + s_sum[1] + s_sum[2] + s_sum[3];
    float Q = s_sq[0] + s_sq[1] + s_sq[2] + s_sq[3];
    float mu = S * (1.0f / HH);
    float var = Q * (1.0f / HH) - mu * mu;
    float rs = rsqrtf(var + 1e-5f);
    out[(size_t)n * HH + t] = f2b((v - mu) * rs * w[t] + b[t]);
}

// ---------------- bf16 MFMA GEMM: C = act(A[M,K] @ BT[N,K]^T + bias) ----------------
template <int OUT_BF16, int ACT>
__global__ __launch_bounds__(256) void k_gemm(
    const u16* __restrict__ A, const u16* __restrict__ BT,
    const float* __restrict__ bias, void* __restrict__ C, int M, int K, int N) {
    __shared__ uint4 As4[512];   // [128 rows][32 k] bf16 = 8 KB
    __shared__ uint4 Bs4[512];
    u16* As = (u16*)As4;
    u16* Bs = (u16*)Bs4;
    int tid = threadIdx.x;
    int wave = tid >> 6, lane = tid & 63;
    int bm = blockIdx.y * 128, bn = blockIdx.x * 128;
    int wm = (wave >> 1) * 64, wn = (wave & 1) * 64;
    int lm = lane & 15;
    int kg = lane >> 4;
    f32x4 acc[4][4] = {};

    for (int k0 = 0; k0 < K; k0 += 32) {
#pragma unroll
        for (int it = 0; it < 2; ++it) {
            int idx = it * 256 + tid;
            int r = idx >> 2, seg = idx & 3;
            As4[idx] = *(const uint4*)&A[(size_t)(bm + r) * K + k0 + seg * 8];
            Bs4[idx] = *(const uint4*)&BT[(size_t)(bn + r) * K + k0 + seg * 8];
        }
        __syncthreads();
        bf16x8 af[4], bfr[4];
#pragma unroll
        for (int i = 0; i < 4; ++i)
            af[i] = *(const bf16x8*)&As[(wm + i * 16 + lm) * 32 + kg * 8];
#pragma unroll
        for (int j = 0; j < 4; ++j)
            bfr[j] = *(const bf16x8*)&Bs[(wn + j * 16 + lm) * 32 + kg * 8];
#pragma unroll
        for (int i = 0; i < 4; ++i)
#pragma unroll
            for (int j = 0; j < 4; ++j)
                acc[i][j] = __builtin_amdgcn_mfma_f32_16x16x32_bf16(af[i], bfr[j], acc[i][j], 0, 0, 0);
        __syncthreads();
    }

#pragma unroll
    for (int j = 0; j < 4; ++j) {
        int col = bn + wn + j * 16 + lm;
        float bv = bias ? bias[col] : 0.f;
#pragma unroll
        for (int i = 0; i < 4; ++i) {
            int row0 = bm + wm + i * 16 + kg * 4;
#pragma unroll
            for (int r = 0; r < 4; ++r) {
                float v = acc[i][j][r] + bv;
                if (ACT) v = silu(v);
                if (OUT_BF16)
                    ((u16*)C)[(size_t)(row0 + r) * N + col] = f2b(v);
                else
                    ((float*)C)[(size_t)(row0 + r) * N + col] = v;
            }
        }
    }
}

// ---------------- message pass: one wave per dst node (CSR gather) ----------------
__global__ __launch_bounds__(256) void k_msg(
    const u16* __restrict__ xhb, const u16* __restrict__ rbfh,
    const u16* __restrict__ vinb, const int* __restrict__ srcp,
    const float4* __restrict__ evp, const int* __restrict__ row_ptr,
    float* __restrict__ dx, float* __restrict__ dvec, int base) {
    int d = blockIdx.x * 4 + (threadIdx.x >> 6);
    int lane = threadIdx.x & 63;
    int r0 = row_ptr[d], r1 = row_ptr[d + 1];
    int e0 = r0 > base ? r0 : base;
    int e1 = r1 < base + ECH ? r1 : base + ECH;
    if (e0 >= e1) return;
    float accx[4] = {};
    float accv[3][4] = {};
    for (int j = e0; j < e1; ++j) {
        int s = srcp[j];
        float4 ev4 = evp[j];
        const ushort4* xr = (const ushort4*)(xhb + (size_t)s * 768);
        const ushort4* rr = (const ushort4*)(rbfh + (size_t)(j - base) * 768);
        const ushort4* vr = (const ushort4*)(vinb + (size_t)s * 768);
        U4 X0, X1, X2, Rr0, Rr1, Rr2, V0, V1, V2;
        X0.v = xr[lane]; X1.v = xr[lane + 64]; X2.v = xr[lane + 128];
        Rr0.v = rr[lane]; Rr1.v = rr[lane + 64]; Rr2.v = rr[lane + 128];
        V0.v = vr[lane]; V1.v = vr[lane + 64]; V2.v = vr[lane + 128];
#pragma unroll
        for (int c = 0; c < 4; ++c) {
            float m0 = b2f(X0.a[c]) * b2f(Rr0.a[c]);
            float m1 = b2f(X1.a[c]) * b2f(Rr1.a[c]) * kInvSqrt3;
            float m2 = b2f(X2.a[c]) * b2f(Rr2.a[c]);
            accx[c] += m0;
            accv[0][c] += b2f(V0.a[c]) * m1 + m2 * ev4.x;
            accv[1][c] += b2f(V1.a[c]) * m1 + m2 * ev4.y;
            accv[2][c] += b2f(V2.a[c]) * m1 + m2 * ev4.z;
        }
    }
#pragma unroll
    for (int k = 0; k < 3; ++k)
#pragma unroll
        for (int c = 0; c < 4; ++c) accv[k][c] *= kInvSqrtH;
    bool interior = (r0 >= base) && (r1 <= base + ECH);
    float* pdx = &dx[(size_t)d * 256 + lane * 4];
    float* pv = &dvec[(size_t)d * 768];
    if (interior) {
        *(float4*)pdx = make_float4(accx[0], accx[1], accx[2], accx[3]);
#pragma unroll
        for (int k = 0; k < 3; ++k)
            *(float4*)&pv[k * 256 + lane * 4] =
                make_float4(accv[k][0], accv[k][1], accv[k][2], accv[k][3]);
    } else {
#pragma unroll
        for (int c = 0; c < 4; ++c) {
            atomicAdd(pdx + c, accx[c]);
#pragma unroll
            for (int k = 0; k < 3; ++k)
                atomicAdd(&pv[k * 256 + lane * 4 + c], accv[k][c]);
        }
    }
}

// ---------------- vout = vin + dvec, emit bf16 ----------------
__global__ void k_finish(const float* __restrict__ vin, const float* __restrict__ dvec,
                         float* __restrict__ vout, u16* __restrict__ vb, int n4) {
    int i = blockIdx.x * 256 + threadIdx.x;
    if (i >= n4) return;
    float4 a = ((const float4*)vin)[i];
    float4 b = ((const float4*)dvec)[i];
    float4 o = make_float4(a.x + b.x, a.y + b.y, a.z + b.z, a.w + b.w);
    ((float4*)vout)[i] = o;
    ushort4 u;
    u.x = f2b(o.x); u.y = f2b(o.y); u.z = f2b(o.z); u.w = f2b(o.w);
    ((ushort4*)vb)[i] = u;
}

// ---------------- x = (x + dx) * 1/sqrt(2) ----------------
__global__ void k_xupdate(float* __restrict__ x, const float* __restrict__ dx) {
    int i = blockIdx.x * 256 + threadIdx.x;
    x[i] = (x[i] + dx[i]) * kInvSqrt2;
}

// ---------------- vec_dot + hcat(bf16) = [x, vnorm] ----------------
__global__ void k_vecdot(const float* __restrict__ vp, const float* __restrict__ x,
                         float* __restrict__ vec_dot, u16* __restrict__ hcat) {
    int i = blockIdx.x * 256 + threadIdx.x;  // N*H
    int n = i >> 8, c = i & 255;
    const float* p = vp + (size_t)n * 1536;
    float dsum = 0.f, qsum = 0.f;
#pragma unroll
    for (int k = 0; k < 3; ++k) {
        float v1 = p[k * 512 + c];
        float v2 = p[k * 512 + 256 + c];
        dsum += v1 * v2;
        qsum += v2 * v2;
    }
    vec_dot[i] = dsum * kInvSqrtH;
    hcat[(size_t)n * 512 + c] = f2b(x[i]);
    hcat[(size_t)n * 512 + 256 + c] = f2b(sqrtf(qsum + 1e-8f));
}

// ---------------- update epilogue (also emits vinb bf16 for next layer) ------------
__global__ void k_update_out(const float* __restrict__ hout, const float* __restrict__ vec_dot,
                             const float* __restrict__ vp, float* __restrict__ x,
                             float* __restrict__ vout, u16* __restrict__ vb) {
    int i = blockIdx.x * 256 + threadIdx.x;  // N*H
    int n = i >> 8, c = i & 255;
    float xv1 = hout[(size_t)n * 768 + c];
    float xv2 = hout[(size_t)n * 768 + 256 + c];
    float xv3 = hout[(size_t)n * 768 + 512 + c];
    float dxv = (xv1 + xv2 * vec_dot[i]) * kInvSqrt2;
    x[i] = (x[i] + dxv) * kInvSqrt2;
#pragma unroll
    for (int k = 0; k < 3; ++k) {
        size_t idx = (size_t)n * 768 + k * 256 + c;
        float nv = vout[idx] + xv3 * vp[(size_t)n * 1536 + k * 512 + c];
        vout[idx] = nv;
        vb[idx] = f2b(nv);
    }
}

// ---------------- energy reduce ----------------
__global__ void k_energy2(const float* __restrict__ h, const float* __restrict__ w2,
                          const float* __restrict__ b2, const int* __restrict__ batch,
                          float* __restrict__ out) {
    int n = blockIdx.x, j = threadIdx.x;   // 128 threads
    float v = h[(size_t)n * 128 + j] * w2[j];
#pragma unroll
    for (int m = 32; m >= 1; m >>= 1) v += __shfl_xor(v, m, 64);
    __shared__ float p[2];
    if ((j & 63) == 0) p[j >> 6] = v;
    __syncthreads();
    if (j == 0) atomicAdd(&out[batch[n]], p[0] + p[1] + b2[0]);
}

extern "C" void kernel_launch(void* const* d_in, const int* in_sizes, int n_in,
                              void* d_out, int out_size, void* d_ws, size_t ws_size,
                              hipStream_t stream) {
    const float* pos      = (const float*)d_in[0];
    const float* atom_emb = (const float*)d_in[1];
    const float* ln_w     = (const float*)d_in[2];
    const float* ln_b     = (const float*)d_in[3];
    const float* xp_w1    = (const float*)d_in[4];
    const float* xp_b1    = (const float*)d_in[5];
    const float* xp_w2    = (const float*)d_in[6];
    const float* xp_b2    = (const float*)d_in[7];
    const float* rbf_w    = (const float*)d_in[8];
    const float* rbf_b    = (const float*)d_in[9];
    const float* vec_w    = (const float*)d_in[10];
    const float* xv_w1    = (const float*)d_in[11];
    const float* xv_b1    = (const float*)d_in[12];
    const float* xv_w2    = (const float*)d_in[13];
    const float* xv_b2    = (const float*)d_in[14];
    const float* oe_w1    = (const float*)d_in[15];
    const float* oe_b1    = (const float*)d_in[16];
    const float* oe_w2    = (const float*)d_in[17];
    const float* oe_b2    = (const float*)d_in[18];
    const int*   z        = (const int*)d_in[19];
    const int*   ei       = (const int*)d_in[20];
    const int*   batch    = (const int*)d_in[21];
    float* out = (float*)d_out;

    char* ws = (char*)d_ws;
    size_t off = 0;
    auto alloc = [&](size_t b) {
        void* p = ws + off;
        off = (off + b + 255) & ~(size_t)255;
        return p;
    };
    float*  ev     = (float*)alloc((size_t)EE * 4 * 4);        //   2 MB
    float*  x      = (float*)alloc((size_t)NN * HH * 4);       //   8 MB
    float*  vecA   = (float*)alloc((size_t)NN * 768 * 4);      //  24 MB
    float*  vecB   = (float*)alloc((size_t)NN * 768 * 4);      //  24 MB
    float*  houtf  = (float*)alloc((size_t)NN * 768 * 4);      //  24 MB
    float*  dx     = (float*)alloc((size_t)NN * HH * 4);       //   8 MB
    float*  dvec   = (float*)alloc((size_t)NN * 768 * 4);      //  24 MB
    float*  scr8   = (float*)alloc((size_t)ECH * RR * 2);      //   8 MB (vdot|rbfcb|heng)
    u16*    hcatb  = (u16*)alloc((size_t)NN * 512 * 2);        //   8 MB
    u16*    xlnb   = (u16*)alloc((size_t)NN * HH * 2);         //   4 MB (alias xb)
    u16*    t1b    = (u16*)alloc((size_t)NN * HH * 2);         //   4 MB
    u16*    h1b    = (u16*)alloc((size_t)NN * HH * 2);         //   4 MB
    u16*    xhb    = (u16*)alloc((size_t)NN * 768 * 2);        //  12 MB
    u16*    vb     = (u16*)alloc((size_t)NN * 768 * 2);        //  12 MB (voutb|vinb)
    float*  big    = (float*)alloc((size_t)NN * 1536 * 4);     //  48 MB (vp | rbfhc)
    // CSR
    int*    deg    = (int*)alloc((size_t)NN * 4);
    int*    row_ptr= (int*)alloc((size_t)(NN + 1) * 4);
    int*    fill   = (int*)alloc((size_t)NN * 4);
    int*    srcp   = (int*)alloc((size_t)EE * 4);
    float4* evp    = (float4*)alloc((size_t)EE * 16);          //   2 MB
    // transposed bf16 weights
    u16* xp_w1T = (u16*)alloc((size_t)3 * 256 * 256 * 2);
    u16* xp_w2T = (u16*)alloc((size_t)3 * 768 * 256 * 2);
    u16* rbf_wT = (u16*)alloc((size_t)3 * 768 * 128 * 2);
    u16* vec_wT = (u16*)alloc((size_t)3 * 512 * 256 * 2);
    u16* xv_w1T = (u16*)alloc((size_t)3 * 256 * 512 * 2);
    u16* xv_w2T = (u16*)alloc((size_t)3 * 768 * 256 * 2);
    u16* oe_w1T = (u16*)alloc((size_t)128 * 256 * 2);
    (void)ws_size;

    float* vp    = big;            // [N,1536] fp32, update phase
    u16*   rbfhc = (u16*)big;      // [ECH,768] bf16, message phase
    float* vdot  = scr8;           // update phase
    u16*   rbfcb = (u16*)scr8;     // message phase [ECH,128] bf16
    float* heng  = scr8;           // energy phase [N,128] fp32
    u16*   xb    = xlnb;

    const int NH4 = NN * HH / 4;
    const int NV4 = NN * 768 / 4;

    // weight transposes (bf16, [N,K] from [K,N])
    for (int l = 0; l < LL; ++l) {
        k_wt<<<dim3(8, 8), 256, 0, stream>>>(xp_w1 + (size_t)l * 256 * 256, xp_w1T + (size_t)l * 256 * 256, 256, 256);
        k_wt<<<dim3(24, 8), 256, 0, stream>>>(xp_w2 + (size_t)l * 256 * 768, xp_w2T + (size_t)l * 768 * 256, 256, 768);
        k_wt<<<dim3(24, 4), 256, 0, stream>>>(rbf_w + (size_t)l * 128 * 768, rbf_wT + (size_t)l * 768 * 128, 128, 768);
        k_wt<<<dim3(16, 8), 256, 0, stream>>>(vec_w + (size_t)l * 256 * 512, vec_wT + (size_t)l * 512 * 256, 256, 512);
        k_wt<<<dim3(8, 16), 256, 0, stream>>>(xv_w1 + (size_t)l * 512 * 256, xv_w1T + (size_t)l * 256 * 512, 512, 256);
        k_wt<<<dim3(24, 8), 256, 0, stream>>>(xv_w2 + (size_t)l * 256 * 768, xv_w2T + (size_t)l * 768 * 256, 256, 768);
    }
    k_wt<<<dim3(4, 8), 256, 0, stream>>>(oe_w1, oe_w1T, 256, 128);

    // init + CSR build
    k_zero<<<(NV4 + 255) / 256, 256, 0, stream>>>(vecA, NV4);
    k_zero<<<((NV4 / 2) + 255) / 256, 256, 0, stream>>>((float*)vb, NV4 / 2);
    k_zero<<<((NN / 4) + 255) / 256, 256, 0, stream>>>((float*)deg, NN / 4);
    k_init_x<<<NN, 256, 0, stream>>>(atom_emb, z, x);
    k_edge_geom<<<EE / 256, 256, 0, stream>>>(pos, ei, ev);
    k_hist<<<EE / 256, 256, 0, stream>>>(ei, deg);
    k_scan<<<1, 256, 0, stream>>>(deg, row_ptr, fill);
    k_scatter<<<EE / 256, 256, 0, stream>>>(ei, ev, fill, srcp, evp);

    float* vin = vecA;
    float* vout = vecB;
    for (int l = 0; l < LL; ++l) {
        // ---- PaiNNMessage ----
        k_ln<<<NN, 256, 0, stream>>>(x, ln_w + l * HH, ln_b + l * HH, xlnb);
        k_gemm<1, 1><<<dim3(2, NN / 128), 256, 0, stream>>>(
            xlnb, xp_w1T + (size_t)l * 256 * 256, xp_b1 + l * HH, t1b, NN, 256, 256);
        k_gemm<1, 0><<<dim3(6, NN / 128), 256, 0, stream>>>(
            t1b, xp_w2T + (size_t)l * 768 * 256, xp_b2 + l * 768, xhb, NN, 256, 768);
        k_zero<<<(NH4 + 255) / 256, 256, 0, stream>>>(dx, NH4);
        k_zero<<<(NV4 + 255) / 256, 256, 0, stream>>>(dvec, NV4);
        for (int c0 = 0; c0 < NCHUNK; ++c0) {
            int base = c0 * ECH;
            k_rbf<<<ECH / 2, 256, 0, stream>>>(evp, rbfcb, base);
            k_gemm<1, 0><<<dim3(6, ECH / 128), 256, 0, stream>>>(
                rbfcb, rbf_wT + (size_t)l * 768 * 128, rbf_b + l * 768, rbfhc, ECH, 128, 768);
            k_msg<<<NN / 4, 256, 0, stream>>>(xhb, rbfhc, vb, srcp, evp, row_ptr, dx, dvec, base);
        }
        k_xupdate<<<NN, 256, 0, stream>>>(x, dx);
        k_finish<<<(NV4 + 255) / 256, 256, 0, stream>>>(vin, dvec, vout, vb, NV4);

        // ---- PaiNNUpdate ----
        k_gemm<0, 0><<<dim3(4, 3 * NN / 128), 256, 0, stream>>>(
            vb, vec_wT + (size_t)l * 512 * 256, nullptr, vp, 3 * NN, 256, 512);
        k_vecdot<<<NN, 256, 0, stream>>>(vp, x, vdot, hcatb);
        k_gemm<1, 1><<<dim3(2, NN / 128), 256, 0, stream>>>(
            hcatb, xv_w1T + (size_t)l * 256 * 512, xv_b1 + l * HH, h1b, NN, 512, 256);
        k_gemm<0, 0><<<dim3(6, NN / 128), 256, 0, stream>>>(
            h1b, xv_w2T + (size_t)l * 768 * 256, xv_b2 + l * 768, houtf, NN, 256, 768);
        k_update_out<<<NN, 256, 0, stream>>>(houtf, vdot, vp, x, vout, vb);

        float* tmp = vin; vin = vout; vout = tmp;
    }

    // ---- energy head ----
    k_b16<<<(NH4 + 255) / 256, 256, 0, stream>>>(xb, x, NH4);
    k_gemm<0, 1><<<dim3(1, NN / 128), 256, 0, stream>>>(
        xb, oe_w1T, oe_b1, heng, NN, 256, 128);
    k_zero<<<1, 256, 0, stream>>>(out, NGG / 4);
    k_energy2<<<NN, 128, 0, stream>>>(heng, oe_w2, oe_b2, batch, out);
}

// Round 5
// 1232.865 us; speedup vs baseline: 3.0045x; 1.1479x over previous
//
#include <hip/hip_runtime.h>
#include <hip/hip_bf16.h>
#include <math.h>

#define NN 8192
#define EE 131072
#define HH 256
#define LL 3
#define RR 128
#define NGG 64
#define ECH 32768            // edge chunk
#define NCHUNK (EE / ECH)    // 4

typedef __attribute__((ext_vector_type(8))) short bf16x8;
typedef __attribute__((ext_vector_type(4))) float f32x4;
typedef unsigned short u16;

union U4 { ushort4 v; unsigned short a[4]; };
union U8 { uint4 v; unsigned short a[8]; };

__device__ __forceinline__ float silu(float v) { return v / (1.0f + expf(-v)); }
__device__ __forceinline__ float b2f(unsigned short u) { return __uint_as_float(((unsigned)u) << 16); }
__device__ __forceinline__ unsigned short f2b(float f) {
    unsigned u = __float_as_uint(f);
    u += 0x7fff + ((u >> 16) & 1);
    return (unsigned short)(u >> 16);
}

constexpr float kInvSqrt2 = 0.70710678118654752440f;
constexpr float kInvSqrt3 = 0.57735026918962576451f;
constexpr float kInvSqrtH = 0.0625f; // 1/sqrt(256)

// ---------------- utility ----------------
__global__ void k_zero(float* __restrict__ p, int n4) {
    int i = blockIdx.x * 256 + threadIdx.x;
    if (i < n4) ((float4*)p)[i] = make_float4(0.f, 0.f, 0.f, 0.f);
}
__global__ void k_b16(u16* __restrict__ o, const float* __restrict__ in, int n4) {
    int i = blockIdx.x * 256 + threadIdx.x;
    if (i >= n4) return;
    float4 v = ((const float4*)in)[i];
    ushort4 u;
    u.x = f2b(v.x); u.y = f2b(v.y); u.z = f2b(v.z); u.w = f2b(v.w);
    ((ushort4*)o)[i] = u;
}

// ---------------- weight transpose: in[K,N] fp32 -> out[N,K] bf16 ----------------
__global__ void k_wt(const float* __restrict__ in, u16* __restrict__ out, int K, int N) {
    __shared__ float tile[32][33];
    int bn = blockIdx.x * 32, bk = blockIdx.y * 32;
    int tx = threadIdx.x & 31, ty = threadIdx.x >> 5;   // 32 x 8
#pragma unroll
    for (int i = 0; i < 32; i += 8)
        tile[ty + i][tx] = in[(size_t)(bk + ty + i) * N + bn + tx];
    __syncthreads();
#pragma unroll
    for (int i = 0; i < 32; i += 8)
        out[(size_t)(bn + ty + i) * K + bk + tx] = f2b(tile[tx][ty + i]);
}

// ---------------- init x = atom_emb[z] ----------------
__global__ void k_init_x(const float* __restrict__ emb, const int* __restrict__ z,
                         float* __restrict__ x) {
    int i = blockIdx.x * 256 + threadIdx.x;
    int n = i >> 8, c = i & 255;
    x[i] = emb[z[n] * HH + c];
}

// ---------------- edge geometry ----------------
__global__ void k_edge_geom(const float* __restrict__ pos, const int* __restrict__ ei,
                            float* __restrict__ ev /*[E,4]*/) {
    int e = blockIdx.x * 256 + threadIdx.x;
    if (e >= EE) return;
    int s = ei[e], d = ei[EE + e];
    float rx = pos[s * 3 + 0] - pos[d * 3 + 0];
    float ry = pos[s * 3 + 1] - pos[d * 3 + 1];
    float rz = pos[s * 3 + 2] - pos[d * 3 + 2];
    float dist = sqrtf(rx * rx + ry * ry + rz * rz);
    float inv = 1.0f / dist;
    ((float4*)ev)[e] = make_float4(rx * inv, ry * inv, rz * inv, dist);
}

// ---------------- CSR build ----------------
__global__ void k_hist(const int* __restrict__ ei, int* __restrict__ deg) {
    int e = blockIdx.x * 256 + threadIdx.x;
    if (e < EE) atomicAdd(&deg[ei[EE + e]], 1);
}
__global__ void k_scan(const int* __restrict__ deg, int* __restrict__ row_ptr,
                       int* __restrict__ fill) {
    __shared__ int buf[256];
    __shared__ int carry_s;
    int t = threadIdx.x;
    if (t == 0) carry_s = 0;
    __syncthreads();
    for (int r = 0; r < NN; r += 256) {
        int v = deg[r + t];
        buf[t] = v;
        __syncthreads();
        for (int ofs = 1; ofs < 256; ofs <<= 1) {
            int add = (t >= ofs) ? buf[t - ofs] : 0;
            __syncthreads();
            buf[t] += add;
            __syncthreads();
        }
        int excl = buf[t] - v;
        int carry = carry_s;
        row_ptr[r + t] = carry + excl;
        fill[r + t] = carry + excl;
        __syncthreads();
        if (t == 255) carry_s = carry + buf[t];
        __syncthreads();
    }
    if (t == 0) row_ptr[NN] = carry_s;
}
__global__ void k_scatter(const int* __restrict__ ei, const float* __restrict__ ev,
                          int* __restrict__ fill, int* __restrict__ srcp,
                          float4* __restrict__ evp) {
    int e = blockIdx.x * 256 + threadIdx.x;
    if (e >= EE) return;
    int d = ei[EE + e];
    int pos = atomicAdd(&fill[d], 1);
    srcp[pos] = ei[e];
    evp[pos] = ((const float4*)ev)[e];
}

// ---------------- LayerNorm -> bf16 ----------------
__global__ void k_ln(const float* __restrict__ x, const float* __restrict__ w,
                     const float* __restrict__ b, u16* __restrict__ out) {
    int n = blockIdx.x, t = threadIdx.x;
    float v = x[(size_t)n * HH + t];
    float s = v, q = v * v;
#pragma unroll
    for (int m = 32; m >= 1; m >>= 1) {
        s += __shfl_xor(s, m, 64);
        q += __shfl_xor(q, m, 64);
    }
    __shared__ float s_sum[4], s_sq[4];
    int wid = t >> 6;
    if ((t & 63) == 0) { s_sum[wid] = s; s_sq[wid] = q; }
    __syncthreads();
    float S = s_sum[0] + s_sum[1] + s_sum[2] + s_sum[3];
    float Q = s_sq[0] + s_sq[1] + s_sq[2] + s_sq[3];
    float mu = S * (1.0f / HH);
    float var = Q * (1.0f / HH) - mu * mu;
    float rs = rsqrtf(var + 1e-5f);
    out[(size_t)n * HH + t] = f2b((v - mu) * rs * w[t] + b[t]);
}

// ---------------- bf16 MFMA GEMM: C = act(A[M,K] @ BT[N,K]^T + bias) ----------------
template <int OUT_BF16, int ACT>
__global__ __launch_bounds__(256) void k_gemm(
    const u16* __restrict__ A, const u16* __restrict__ BT,
    const float* __restrict__ bias, void* __restrict__ C, int M, int K, int N) {
    __shared__ uint4 As4[512];   // [128 rows][32 k] bf16 = 8 KB
    __shared__ uint4 Bs4[512];
    u16* As = (u16*)As4;
    u16* Bs = (u16*)Bs4;
    int tid = threadIdx.x;
    int wave = tid >> 6, lane = tid & 63;
    int bm = blockIdx.y * 128, bn = blockIdx.x * 128;
    int wm = (wave >> 1) * 64, wn = (wave & 1) * 64;
    int lm = lane & 15;
    int kg = lane >> 4;
    f32x4 acc[4][4] = {};

    for (int k0 = 0; k0 < K; k0 += 32) {
#pragma unroll
        for (int it = 0; it < 2; ++it) {
            int idx = it * 256 + tid;
            int r = idx >> 2, seg = idx & 3;
            As4[idx] = *(const uint4*)&A[(size_t)(bm + r) * K + k0 + seg * 8];
            Bs4[idx] = *(const uint4*)&BT[(size_t)(bn + r) * K + k0 + seg * 8];
        }
        __syncthreads();
        bf16x8 af[4], bfr[4];
#pragma unroll
        for (int i = 0; i < 4; ++i)
            af[i] = *(const bf16x8*)&As[(wm + i * 16 + lm) * 32 + kg * 8];
#pragma unroll
        for (int j = 0; j < 4; ++j)
            bfr[j] = *(const bf16x8*)&Bs[(wn + j * 16 + lm) * 32 + kg * 8];
#pragma unroll
        for (int i = 0; i < 4; ++i)
#pragma unroll
            for (int j = 0; j < 4; ++j)
                acc[i][j] = __builtin_amdgcn_mfma_f32_16x16x32_bf16(af[i], bfr[j], acc[i][j], 0, 0, 0);
        __syncthreads();
    }

#pragma unroll
    for (int j = 0; j < 4; ++j) {
        int col = bn + wn + j * 16 + lm;
        float bv = bias ? bias[col] : 0.f;
#pragma unroll
        for (int i = 0; i < 4; ++i) {
            int row0 = bm + wm + i * 16 + kg * 4;
#pragma unroll
            for (int r = 0; r < 4; ++r) {
                float v = acc[i][j][r] + bv;
                if (ACT) v = silu(v);
                if (OUT_BF16)
                    ((u16*)C)[(size_t)(row0 + r) * N + col] = f2b(v);
                else
                    ((float*)C)[(size_t)(row0 + r) * N + col] = v;
            }
        }
    }
}

// ---------------- fused RBF + GEMM: rbfh = gauss(evp.dist) @ rbf_wT^T + bias --------
// A tile [128 edges][K=128] computed in-register (exp), B = rbf_wT [768][128] bf16.
__global__ __launch_bounds__(256) void k_rbfgemm(
    const float4* __restrict__ evp, const u16* __restrict__ BT,
    const float* __restrict__ bias, u16* __restrict__ C, int base) {
    __shared__ uint4 As4[512];
    __shared__ uint4 Bs4[512];
    u16* As = (u16*)As4;
    u16* Bs = (u16*)Bs4;
    const float step = 12.0f / 127.0f;
    const float coeff = -0.5f / (step * step);
    int tid = threadIdx.x;
    int wave = tid >> 6, lane = tid & 63;
    int bm = blockIdx.y * 128, bn = blockIdx.x * 128;
    int wm = (wave >> 1) * 64, wn = (wave & 1) * 64;
    int lm = lane & 15;
    int kg = lane >> 4;
    f32x4 acc[4][4] = {};

    for (int k0 = 0; k0 < RR; k0 += 32) {
#pragma unroll
        for (int it = 0; it < 2; ++it) {
            int idx = it * 256 + tid;
            int r = idx >> 2, seg = idx & 3;
            float d = evp[base + bm + r].w;
            U8 a;
#pragma unroll
            for (int j = 0; j < 8; ++j) {
                float t = d - (k0 + seg * 8 + j) * step;
                a.a[j] = f2b(expf(coeff * t * t));
            }
            As4[idx] = a.v;
            Bs4[idx] = *(const uint4*)&BT[(size_t)(bn + r) * RR + k0 + seg * 8];
        }
        __syncthreads();
        bf16x8 af[4], bfr[4];
#pragma unroll
        for (int i = 0; i < 4; ++i)
            af[i] = *(const bf16x8*)&As[(wm + i * 16 + lm) * 32 + kg * 8];
#pragma unroll
        for (int j = 0; j < 4; ++j)
            bfr[j] = *(const bf16x8*)&Bs[(wn + j * 16 + lm) * 32 + kg * 8];
#pragma unroll
        for (int i = 0; i < 4; ++i)
#pragma unroll
            for (int j = 0; j < 4; ++j)
                acc[i][j] = __builtin_amdgcn_mfma_f32_16x16x32_bf16(af[i], bfr[j], acc[i][j], 0, 0, 0);
        __syncthreads();
    }

#pragma unroll
    for (int j = 0; j < 4; ++j) {
        int col = bn + wn + j * 16 + lm;
        float bv = bias[col];
#pragma unroll
        for (int i = 0; i < 4; ++i) {
            int row0 = bm + wm + i * 16 + kg * 4;
#pragma unroll
            for (int r = 0; r < 4; ++r)
                C[(size_t)(row0 + r) * 768 + col] = f2b(acc[i][j][r] + bv);
        }
    }
}

// ---------------- message pass: one wave per dst node (CSR gather) ----------------
__global__ __launch_bounds__(256) void k_msg(
    const u16* __restrict__ xhb, const u16* __restrict__ rbfh,
    const u16* __restrict__ vinb, const int* __restrict__ srcp,
    const float4* __restrict__ evp, const int* __restrict__ row_ptr,
    float* __restrict__ dx, float* __restrict__ dvec, int base) {
    int d = blockIdx.x * 4 + (threadIdx.x >> 6);
    int lane = threadIdx.x & 63;
    int r0 = row_ptr[d], r1 = row_ptr[d + 1];
    int e0 = r0 > base ? r0 : base;
    int e1 = r1 < base + ECH ? r1 : base + ECH;
    if (e0 >= e1) return;
    float accx[4] = {};
    float accv[3][4] = {};
    for (int j = e0; j < e1; ++j) {
        int s = srcp[j];
        float4 ev4 = evp[j];
        const ushort4* xr = (const ushort4*)(xhb + (size_t)s * 768);
        const ushort4* rr = (const ushort4*)(rbfh + (size_t)(j - base) * 768);
        const ushort4* vr = (const ushort4*)(vinb + (size_t)s * 768);
        U4 X0, X1, X2, Rr0, Rr1, Rr2, V0, V1, V2;
        X0.v = xr[lane]; X1.v = xr[lane + 64]; X2.v = xr[lane + 128];
        Rr0.v = rr[lane]; Rr1.v = rr[lane + 64]; Rr2.v = rr[lane + 128];
        V0.v = vr[lane]; V1.v = vr[lane + 64]; V2.v = vr[lane + 128];
#pragma unroll
        for (int c = 0; c < 4; ++c) {
            float m0 = b2f(X0.a[c]) * b2f(Rr0.a[c]);
            float m1 = b2f(X1.a[c]) * b2f(Rr1.a[c]) * kInvSqrt3;
            float m2 = b2f(X2.a[c]) * b2f(Rr2.a[c]);
            accx[c] += m0;
            accv[0][c] += b2f(V0.a[c]) * m1 + m2 * ev4.x;
            accv[1][c] += b2f(V1.a[c]) * m1 + m2 * ev4.y;
            accv[2][c] += b2f(V2.a[c]) * m1 + m2 * ev4.z;
        }
    }
#pragma unroll
    for (int k = 0; k < 3; ++k)
#pragma unroll
        for (int c = 0; c < 4; ++c) accv[k][c] *= kInvSqrtH;
    bool interior = (r0 >= base) && (r1 <= base + ECH);
    float* pdx = &dx[(size_t)d * 256 + lane * 4];
    float* pv = &dvec[(size_t)d * 768];
    if (interior) {
        *(float4*)pdx = make_float4(accx[0], accx[1], accx[2], accx[3]);
#pragma unroll
        for (int k = 0; k < 3; ++k)
            *(float4*)&pv[k * 256 + lane * 4] =
                make_float4(accv[k][0], accv[k][1], accv[k][2], accv[k][3]);
    } else {
#pragma unroll
        for (int c = 0; c < 4; ++c) {
            atomicAdd(pdx + c, accx[c]);
#pragma unroll
            for (int k = 0; k < 3; ++k)
                atomicAdd(&pv[k * 256 + lane * 4 + c], accv[k][c]);
        }
    }
}

// ---------------- vout = vin + dvec, emit bf16 ----------------
__global__ void k_finish(const float* __restrict__ vin, const float* __restrict__ dvec,
                         float* __restrict__ vout, u16* __restrict__ vb, int n4) {
    int i = blockIdx.x * 256 + threadIdx.x;
    if (i >= n4) return;
    float4 a = ((const float4*)vin)[i];
    float4 b = ((const float4*)dvec)[i];
    float4 o = make_float4(a.x + b.x, a.y + b.y, a.z + b.z, a.w + b.w);
    ((float4*)vout)[i] = o;
    ushort4 u;
    u.x = f2b(o.x); u.y = f2b(o.y); u.z = f2b(o.z); u.w = f2b(o.w);
    ((ushort4*)vb)[i] = u;
}

// ---------------- x = (x + dx) * 1/sqrt(2) ----------------
__global__ void k_xupdate(float* __restrict__ x, const float* __restrict__ dx) {
    int i = blockIdx.x * 256 + threadIdx.x;
    x[i] = (x[i] + dx[i]) * kInvSqrt2;
}

// ---------------- vec_dot + hcat(bf16) = [x, vnorm]; vp in bf16 -------------------
__global__ void k_vecdot(const u16* __restrict__ vp, const float* __restrict__ x,
                         float* __restrict__ vec_dot, u16* __restrict__ hcat) {
    int i = blockIdx.x * 256 + threadIdx.x;  // N*H
    int n = i >> 8, c = i & 255;
    const u16* p = vp + (size_t)n * 1536;
    float dsum = 0.f, qsum = 0.f;
#pragma unroll
    for (int k = 0; k < 3; ++k) {
        float v1 = b2f(p[k * 512 + c]);
        float v2 = b2f(p[k * 512 + 256 + c]);
        dsum += v1 * v2;
        qsum += v2 * v2;
    }
    vec_dot[i] = dsum * kInvSqrtH;
    hcat[(size_t)n * 512 + c] = f2b(x[i]);
    hcat[(size_t)n * 512 + 256 + c] = f2b(sqrtf(qsum + 1e-8f));
}

// ---------------- update epilogue (hout/vp bf16; emits vb bf16) --------------------
__global__ void k_update_out(const u16* __restrict__ hout, const float* __restrict__ vec_dot,
                             const u16* __restrict__ vp, float* __restrict__ x,
                             float* __restrict__ vout, u16* __restrict__ vb) {
    int i = blockIdx.x * 256 + threadIdx.x;  // N*H
    int n = i >> 8, c = i & 255;
    float xv1 = b2f(hout[(size_t)n * 768 + c]);
    float xv2 = b2f(hout[(size_t)n * 768 + 256 + c]);
    float xv3 = b2f(hout[(size_t)n * 768 + 512 + c]);
    float dxv = (xv1 + xv2 * vec_dot[i]) * kInvSqrt2;
    x[i] = (x[i] + dxv) * kInvSqrt2;
#pragma unroll
    for (int k = 0; k < 3; ++k) {
        size_t idx = (size_t)n * 768 + k * 256 + c;
        float nv = vout[idx] + xv3 * b2f(vp[(size_t)n * 1536 + k * 512 + c]);
        vout[idx] = nv;
        vb[idx] = f2b(nv);
    }
}

// ---------------- energy reduce: LDS segment sum (batch sorted), few atomics -------
__global__ void k_energy2(const float* __restrict__ h, const float* __restrict__ w2,
                          const float* __restrict__ b2, const int* __restrict__ batch,
                          float* __restrict__ out) {
    __shared__ float g[NGG];
    int t = threadIdx.x;
    if (t < NGG) g[t] = 0.f;
    __syncthreads();
    int a = blockIdx.x * 256 + t;             // 32 blocks x 256 threads = 8192 atoms
    const float4* hr = (const float4*)(h + (size_t)a * 128);
    const float4* w4 = (const float4*)w2;
    float acc = 0.f;
#pragma unroll 8
    for (int i = 0; i < 32; ++i) {
        float4 hv = hr[i], wv = w4[i];
        acc += hv.x * wv.x + hv.y * wv.y + hv.z * wv.z + hv.w * wv.w;
    }
    acc += b2[0];
    atomicAdd(&g[batch[a]], acc);
    __syncthreads();
    if (t < NGG && g[t] != 0.f) atomicAdd(&out[t], g[t]);
}

extern "C" void kernel_launch(void* const* d_in, const int* in_sizes, int n_in,
                              void* d_out, int out_size, void* d_ws, size_t ws_size,
                              hipStream_t stream) {
    const float* pos      = (const float*)d_in[0];
    const float* atom_emb = (const float*)d_in[1];
    const float* ln_w     = (const float*)d_in[2];
    const float* ln_b     = (const float*)d_in[3];
    const float* xp_w1    = (const float*)d_in[4];
    const float* xp_b1    = (const float*)d_in[5];
    const float* xp_w2    = (const float*)d_in[6];
    const float* xp_b2    = (const float*)d_in[7];
    const float* rbf_w    = (const float*)d_in[8];
    const float* rbf_b    = (const float*)d_in[9];
    const float* vec_w    = (const float*)d_in[10];
    const float* xv_w1    = (const float*)d_in[11];
    const float* xv_b1    = (const float*)d_in[12];
    const float* xv_w2    = (const float*)d_in[13];
    const float* xv_b2    = (const float*)d_in[14];
    const float* oe_w1    = (const float*)d_in[15];
    const float* oe_b1    = (const float*)d_in[16];
    const float* oe_w2    = (const float*)d_in[17];
    const float* oe_b2    = (const float*)d_in[18];
    const int*   z        = (const int*)d_in[19];
    const int*   ei       = (const int*)d_in[20];
    const int*   batch    = (const int*)d_in[21];
    float* out = (float*)d_out;

    char* ws = (char*)d_ws;
    size_t off = 0;
    auto alloc = [&](size_t b) {
        void* p = ws + off;
        off = (off + b + 255) & ~(size_t)255;
        return p;
    };
    float*  ev     = (float*)alloc((size_t)EE * 4 * 4);        //   2 MB
    float*  x      = (float*)alloc((size_t)NN * HH * 4);       //   8 MB
    float*  vecA   = (float*)alloc((size_t)NN * 768 * 4);      //  24 MB
    float*  vecB   = (float*)alloc((size_t)NN * 768 * 4);      //  24 MB
    u16*    houtb  = (u16*)alloc((size_t)NN * 768 * 2);        //  12 MB
    float*  dx     = (float*)alloc((size_t)NN * HH * 4);       //   8 MB
    float*  dvec   = (float*)alloc((size_t)NN * 768 * 4);      //  24 MB
    float*  scr8   = (float*)alloc((size_t)NN * HH * 4);       //   8 MB (vdot | heng)
    u16*    hcatb  = (u16*)alloc((size_t)NN * 512 * 2);        //   8 MB
    u16*    xlnb   = (u16*)alloc((size_t)NN * HH * 2);         //   4 MB (alias xb)
    u16*    t1b    = (u16*)alloc((size_t)NN * HH * 2);         //   4 MB
    u16*    h1b    = (u16*)alloc((size_t)NN * HH * 2);         //   4 MB
    u16*    xhb    = (u16*)alloc((size_t)NN * 768 * 2);        //  12 MB
    u16*    vb     = (u16*)alloc((size_t)NN * 768 * 2);        //  12 MB
    float*  big    = (float*)alloc((size_t)NN * 1536 * 4);     //  48 MB (vpb | rbfhc)
    // CSR
    int*    deg    = (int*)alloc((size_t)NN * 4);
    int*    row_ptr= (int*)alloc((size_t)(NN + 1) * 4);
    int*    fill   = (int*)alloc((size_t)NN * 4);
    int*    srcp   = (int*)alloc((size_t)EE * 4);
    float4* evp    = (float4*)alloc((size_t)EE * 16);          //   2 MB
    // transposed bf16 weights
    u16* xp_w1T = (u16*)alloc((size_t)3 * 256 * 256 * 2);
    u16* xp_w2T = (u16*)alloc((size_t)3 * 768 * 256 * 2);
    u16* rbf_wT = (u16*)alloc((size_t)3 * 768 * 128 * 2);
    u16* vec_wT = (u16*)alloc((size_t)3 * 512 * 256 * 2);
    u16* xv_w1T = (u16*)alloc((size_t)3 * 256 * 512 * 2);
    u16* xv_w2T = (u16*)alloc((size_t)3 * 768 * 256 * 2);
    u16* oe_w1T = (u16*)alloc((size_t)128 * 256 * 2);
    (void)ws_size;

    u16*   vpb   = (u16*)big;      // [N,1536] bf16, update phase
    u16*   rbfhc = (u16*)big;      // [ECH,768] bf16, message phase
    float* vdot  = scr8;           // update phase [N,256] fp32
    float* heng  = scr8;           // energy phase [N,128] fp32
    u16*   xb    = xlnb;

    const int NH4 = NN * HH / 4;
    const int NV4 = NN * 768 / 4;

    // weight transposes (bf16, [N,K] from [K,N])
    for (int l = 0; l < LL; ++l) {
        k_wt<<<dim3(8, 8), 256, 0, stream>>>(xp_w1 + (size_t)l * 256 * 256, xp_w1T + (size_t)l * 256 * 256, 256, 256);
        k_wt<<<dim3(24, 8), 256, 0, stream>>>(xp_w2 + (size_t)l * 256 * 768, xp_w2T + (size_t)l * 768 * 256, 256, 768);
        k_wt<<<dim3(24, 4), 256, 0, stream>>>(rbf_w + (size_t)l * 128 * 768, rbf_wT + (size_t)l * 768 * 128, 128, 768);
        k_wt<<<dim3(16, 8), 256, 0, stream>>>(vec_w + (size_t)l * 256 * 512, vec_wT + (size_t)l * 512 * 256, 256, 512);
        k_wt<<<dim3(8, 16), 256, 0, stream>>>(xv_w1 + (size_t)l * 512 * 256, xv_w1T + (size_t)l * 256 * 512, 512, 256);
        k_wt<<<dim3(24, 8), 256, 0, stream>>>(xv_w2 + (size_t)l * 256 * 768, xv_w2T + (size_t)l * 768 * 256, 256, 768);
    }
    k_wt<<<dim3(4, 8), 256, 0, stream>>>(oe_w1, oe_w1T, 256, 128);

    // init + CSR build
    k_zero<<<(NV4 + 255) / 256, 256, 0, stream>>>(vecA, NV4);
    k_zero<<<((NV4 / 2) + 255) / 256, 256, 0, stream>>>((float*)vb, NV4 / 2);
    k_zero<<<((NN / 4) + 255) / 256, 256, 0, stream>>>((float*)deg, NN / 4);
    k_init_x<<<NN, 256, 0, stream>>>(atom_emb, z, x);
    k_edge_geom<<<EE / 256, 256, 0, stream>>>(pos, ei, ev);
    k_hist<<<EE / 256, 256, 0, stream>>>(ei, deg);
    k_scan<<<1, 256, 0, stream>>>(deg, row_ptr, fill);
    k_scatter<<<EE / 256, 256, 0, stream>>>(ei, ev, fill, srcp, evp);

    float* vin = vecA;
    float* vout = vecB;
    for (int l = 0; l < LL; ++l) {
        // ---- PaiNNMessage ----
        k_ln<<<NN, 256, 0, stream>>>(x, ln_w + l * HH, ln_b + l * HH, xlnb);
        k_gemm<1, 1><<<dim3(2, NN / 128), 256, 0, stream>>>(
            xlnb, xp_w1T + (size_t)l * 256 * 256, xp_b1 + l * HH, t1b, NN, 256, 256);
        k_gemm<1, 0><<<dim3(6, NN / 128), 256, 0, stream>>>(
            t1b, xp_w2T + (size_t)l * 768 * 256, xp_b2 + l * 768, xhb, NN, 256, 768);
        k_zero<<<(NH4 + 255) / 256, 256, 0, stream>>>(dx, NH4);
        k_zero<<<(NV4 + 255) / 256, 256, 0, stream>>>(dvec, NV4);
        for (int c0 = 0; c0 < NCHUNK; ++c0) {
            int base = c0 * ECH;
            k_rbfgemm<<<dim3(6, ECH / 128), 256, 0, stream>>>(
                evp, rbf_wT + (size_t)l * 768 * 128, rbf_b + l * 768, rbfhc, base);
            k_msg<<<NN / 4, 256, 0, stream>>>(xhb, rbfhc, vb, srcp, evp, row_ptr, dx, dvec, base);
        }
        k_xupdate<<<NN, 256, 0, stream>>>(x, dx);
        k_finish<<<(NV4 + 255) / 256, 256, 0, stream>>>(vin, dvec, vout, vb, NV4);

        // ---- PaiNNUpdate ----
        k_gemm<1, 0><<<dim3(4, 3 * NN / 128), 256, 0, stream>>>(
            vb, vec_wT + (size_t)l * 512 * 256, nullptr, vpb, 3 * NN, 256, 512);
        k_vecdot<<<NN, 256, 0, stream>>>(vpb, x, vdot, hcatb);
        k_gemm<1, 1><<<dim3(2, NN / 128), 256, 0, stream>>>(
            hcatb, xv_w1T + (size_t)l * 256 * 512, xv_b1 + l * HH, h1b, NN, 512, 256);
        k_gemm<1, 0><<<dim3(6, NN / 128), 256, 0, stream>>>(
            h1b, xv_w2T + (size_t)l * 768 * 256, xv_b2 + l * 768, houtb, NN, 256, 768);
        k_update_out<<<NN, 256, 0, stream>>>(houtb, vdot, vpb, x, vout, vb);

        float* tmp = vin; vin = vout; vout = tmp;
    }

    // ---- energy head ----
    k_b16<<<(NH4 + 255) / 256, 256, 0, stream>>>(xb, x, NH4);
    k_gemm<0, 1><<<dim3(1, NN / 128), 256, 0, stream>>>(
        xb, oe_w1T, oe_b1, heng, NN, 256, 128);
    k_zero<<<1, 256, 0, stream>>>(out, NGG / 4);
    k_energy2<<<32, 256, 0, stream>>>(heng, oe_w2, oe_b2, batch, out);
}

// Round 6
// 1085.907 us; speedup vs baseline: 3.4111x; 1.1353x over previous
//
#include <hip/hip_runtime.h>
#include <hip/hip_bf16.h>
#include <math.h>

#define NN 8192
#define EE 131072
#define HH 256
#define LL 3
#define RR 128
#define NGG 64
#define ECH 65536            // edge chunk
#define NCHUNK (EE / ECH)    // 2

typedef __attribute__((ext_vector_type(8))) short bf16x8;
typedef __attribute__((ext_vector_type(4))) float f32x4;
typedef unsigned short u16;

union U4 { ushort4 v; unsigned short a[4]; };
union U8 { uint4 v; unsigned short a[8]; };

__device__ __forceinline__ float silu(float v) { return v / (1.0f + expf(-v)); }
__device__ __forceinline__ float b2f(unsigned short u) { return __uint_as_float(((unsigned)u) << 16); }
__device__ __forceinline__ unsigned short f2b(float f) {
    unsigned u = __float_as_uint(f);
    u += 0x7fff + ((u >> 16) & 1);
    return (unsigned short)(u >> 16);
}

constexpr float kInvSqrt2 = 0.70710678118654752440f;
constexpr float kInvSqrt3 = 0.57735026918962576451f;
constexpr float kInvSqrtH = 0.0625f; // 1/sqrt(256)

// ---------------- utility ----------------
__global__ void k_zero(float* __restrict__ p, int n4) {
    int i = blockIdx.x * 256 + threadIdx.x;
    if (i < n4) ((float4*)p)[i] = make_float4(0.f, 0.f, 0.f, 0.f);
}

// ---------------- ALL weight transposes in one launch ----------------
// maps blockIdx.x -> (matrix, layer, 32x32 tile); in[K,N] fp32 -> out[N,K] bf16
__global__ __launch_bounds__(256) void k_wt_all(
    const float* __restrict__ xp_w1, const float* __restrict__ xp_w2,
    const float* __restrict__ rbf_w, const float* __restrict__ vec_w,
    const float* __restrict__ xv_w1, const float* __restrict__ xv_w2,
    const float* __restrict__ oe_w1,
    u16* __restrict__ xp_w1T, u16* __restrict__ xp_w2T, u16* __restrict__ rbf_wT,
    u16* __restrict__ vec_wT, u16* __restrict__ xv_w1T, u16* __restrict__ xv_w2T,
    u16* __restrict__ oe_w1T) {
    int bid = blockIdx.x;
    const float* src; u16* dst; int K, N, t;
    if (bid < 2400) {
        int l = bid / 800, r = bid % 800;
        if (r < 64)       { src = xp_w1 + (size_t)l * 65536;  dst = xp_w1T + (size_t)l * 65536;  K = 256; N = 256; t = r; }
        else if (r < 256) { src = xp_w2 + (size_t)l * 196608; dst = xp_w2T + (size_t)l * 196608; K = 256; N = 768; t = r - 64; }
        else if (r < 352) { src = rbf_w + (size_t)l * 98304;  dst = rbf_wT + (size_t)l * 98304;  K = 128; N = 768; t = r - 256; }
        else if (r < 480) { src = vec_w + (size_t)l * 131072; dst = vec_wT + (size_t)l * 131072; K = 256; N = 512; t = r - 352; }
        else if (r < 608) { src = xv_w1 + (size_t)l * 131072; dst = xv_w1T + (size_t)l * 131072; K = 512; N = 256; t = r - 480; }
        else              { src = xv_w2 + (size_t)l * 196608; dst = xv_w2T + (size_t)l * 196608; K = 256; N = 768; t = r - 608; }
    } else {
        src = oe_w1; dst = oe_w1T; K = 256; N = 128; t = bid - 2400;
    }
    int nx = N >> 5;
    int bn = (t % nx) * 32, bk = (t / nx) * 32;
    __shared__ float tile[32][33];
    int tx = threadIdx.x & 31, ty = threadIdx.x >> 5;   // 32 x 8
#pragma unroll
    for (int i = 0; i < 32; i += 8)
        tile[ty + i][tx] = src[(size_t)(bk + ty + i) * N + bn + tx];
    __syncthreads();
#pragma unroll
    for (int i = 0; i < 32; i += 8)
        dst[(size_t)(bn + ty + i) * K + bk + tx] = f2b(tile[tx][ty + i]);
}

// ---------------- init: x = atom_emb[z], + LayerNorm(ln[0]) -> xlnb ----------------
__global__ void k_init_ln(const float* __restrict__ emb, const int* __restrict__ z,
                          const float* __restrict__ w, const float* __restrict__ b,
                          float* __restrict__ x, u16* __restrict__ xlnb) {
    int n = blockIdx.x, t = threadIdx.x;
    float v = emb[z[n] * HH + t];
    x[(size_t)n * HH + t] = v;
    float s = v, q = v * v;
#pragma unroll
    for (int m = 32; m >= 1; m >>= 1) {
        s += __shfl_xor(s, m, 64);
        q += __shfl_xor(q, m, 64);
    }
    __shared__ float s_sum[4], s_sq[4];
    int wid = t >> 6;
    if ((t & 63) == 0) { s_sum[wid] = s; s_sq[wid] = q; }
    __syncthreads();
    float S = s_sum[0] + s_sum[1] + s_sum[2] + s_sum[3];
    float Q = s_sq[0] + s_sq[1] + s_sq[2] + s_sq[3];
    float mu = S * (1.0f / HH);
    float var = Q * (1.0f / HH) - mu * mu;
    float rs = rsqrtf(var + 1e-5f);
    xlnb[(size_t)n * HH + t] = f2b((v - mu) * rs * w[t] + b[t]);
}

// ---------------- edge geometry ----------------
__global__ void k_edge_geom(const float* __restrict__ pos, const int* __restrict__ ei,
                            float* __restrict__ ev /*[E,4]*/) {
    int e = blockIdx.x * 256 + threadIdx.x;
    if (e >= EE) return;
    int s = ei[e], d = ei[EE + e];
    float rx = pos[s * 3 + 0] - pos[d * 3 + 0];
    float ry = pos[s * 3 + 1] - pos[d * 3 + 1];
    float rz = pos[s * 3 + 2] - pos[d * 3 + 2];
    float dist = sqrtf(rx * rx + ry * ry + rz * rz);
    float inv = 1.0f / dist;
    ((float4*)ev)[e] = make_float4(rx * inv, ry * inv, rz * inv, dist);
}

// ---------------- CSR build ----------------
__global__ void k_hist(const int* __restrict__ ei, int* __restrict__ deg) {
    int e = blockIdx.x * 256 + threadIdx.x;
    if (e < EE) atomicAdd(&deg[ei[EE + e]], 1);
}
__global__ void k_scan(const int* __restrict__ deg, int* __restrict__ row_ptr,
                       int* __restrict__ fill) {
    __shared__ int buf[256];
    __shared__ int carry_s;
    int t = threadIdx.x;
    if (t == 0) carry_s = 0;
    __syncthreads();
    for (int r = 0; r < NN; r += 256) {
        int v = deg[r + t];
        buf[t] = v;
        __syncthreads();
        for (int ofs = 1; ofs < 256; ofs <<= 1) {
            int add = (t >= ofs) ? buf[t - ofs] : 0;
            __syncthreads();
            buf[t] += add;
            __syncthreads();
        }
        int excl = buf[t] - v;
        int carry = carry_s;
        row_ptr[r + t] = carry + excl;
        fill[r + t] = carry + excl;
        __syncthreads();
        if (t == 255) carry_s = carry + buf[t];
        __syncthreads();
    }
    if (t == 0) row_ptr[NN] = carry_s;
}
__global__ void k_scatter(const int* __restrict__ ei, const float* __restrict__ ev,
                          int* __restrict__ fill, int* __restrict__ srcp,
                          float4* __restrict__ evp) {
    int e = blockIdx.x * 256 + threadIdx.x;
    if (e >= EE) return;
    int d = ei[EE + e];
    int pos = atomicAdd(&fill[d], 1);
    srcp[pos] = ei[e];
    evp[pos] = ((const float4*)ev)[e];
}

// ---------------- bf16 MFMA GEMM: C = act(A[M,K] @ BT[N,K]^T + bias) ----------------
template <int OUT_BF16, int ACT>
__global__ __launch_bounds__(256) void k_gemm(
    const u16* __restrict__ A, const u16* __restrict__ BT,
    const float* __restrict__ bias, void* __restrict__ C, int M, int K, int N) {
    __shared__ uint4 As4[512];   // [128 rows][32 k] bf16 = 8 KB
    __shared__ uint4 Bs4[512];
    u16* As = (u16*)As4;
    u16* Bs = (u16*)Bs4;
    int tid = threadIdx.x;
    int wave = tid >> 6, lane = tid & 63;
    int bm = blockIdx.y * 128, bn = blockIdx.x * 128;
    int wm = (wave >> 1) * 64, wn = (wave & 1) * 64;
    int lm = lane & 15;
    int kg = lane >> 4;
    f32x4 acc[4][4] = {};

    for (int k0 = 0; k0 < K; k0 += 32) {
#pragma unroll
        for (int it = 0; it < 2; ++it) {
            int idx = it * 256 + tid;
            int r = idx >> 2, seg = idx & 3;
            As4[idx] = *(const uint4*)&A[(size_t)(bm + r) * K + k0 + seg * 8];
            Bs4[idx] = *(const uint4*)&BT[(size_t)(bn + r) * K + k0 + seg * 8];
        }
        __syncthreads();
        bf16x8 af[4], bfr[4];
#pragma unroll
        for (int i = 0; i < 4; ++i)
            af[i] = *(const bf16x8*)&As[(wm + i * 16 + lm) * 32 + kg * 8];
#pragma unroll
        for (int j = 0; j < 4; ++j)
            bfr[j] = *(const bf16x8*)&Bs[(wn + j * 16 + lm) * 32 + kg * 8];
#pragma unroll
        for (int i = 0; i < 4; ++i)
#pragma unroll
            for (int j = 0; j < 4; ++j)
                acc[i][j] = __builtin_amdgcn_mfma_f32_16x16x32_bf16(af[i], bfr[j], acc[i][j], 0, 0, 0);
        __syncthreads();
    }

#pragma unroll
    for (int j = 0; j < 4; ++j) {
        int col = bn + wn + j * 16 + lm;
        float bv = bias ? bias[col] : 0.f;
#pragma unroll
        for (int i = 0; i < 4; ++i) {
            int row0 = bm + wm + i * 16 + kg * 4;
#pragma unroll
            for (int r = 0; r < 4; ++r) {
                float v = acc[i][j][r] + bv;
                if (ACT) v = silu(v);
                if (OUT_BF16)
                    ((u16*)C)[(size_t)(row0 + r) * N + col] = f2b(v);
                else
                    ((float*)C)[(size_t)(row0 + r) * N + col] = v;
            }
        }
    }
}

// ---------------- fused RBF + GEMM: rbfh = gauss(evp.dist) @ rbf_wT^T + bias --------
__global__ __launch_bounds__(256) void k_rbfgemm(
    const float4* __restrict__ evp, const u16* __restrict__ BT,
    const float* __restrict__ bias, u16* __restrict__ C, int base) {
    __shared__ uint4 As4[512];
    __shared__ uint4 Bs4[512];
    u16* As = (u16*)As4;
    u16* Bs = (u16*)Bs4;
    const float step = 12.0f / 127.0f;
    const float coeff = -0.5f / (step * step);
    int tid = threadIdx.x;
    int wave = tid >> 6, lane = tid & 63;
    int bm = blockIdx.y * 128, bn = blockIdx.x * 128;
    int wm = (wave >> 1) * 64, wn = (wave & 1) * 64;
    int lm = lane & 15;
    int kg = lane >> 4;
    f32x4 acc[4][4] = {};

    for (int k0 = 0; k0 < RR; k0 += 32) {
#pragma unroll
        for (int it = 0; it < 2; ++it) {
            int idx = it * 256 + tid;
            int r = idx >> 2, seg = idx & 3;
            float d = evp[base + bm + r].w;
            U8 a;
#pragma unroll
            for (int j = 0; j < 8; ++j) {
                float t = d - (k0 + seg * 8 + j) * step;
                a.a[j] = f2b(expf(coeff * t * t));
            }
            As4[idx] = a.v;
            Bs4[idx] = *(const uint4*)&BT[(size_t)(bn + r) * RR + k0 + seg * 8];
        }
        __syncthreads();
        bf16x8 af[4], bfr[4];
#pragma unroll
        for (int i = 0; i < 4; ++i)
            af[i] = *(const bf16x8*)&As[(wm + i * 16 + lm) * 32 + kg * 8];
#pragma unroll
        for (int j = 0; j < 4; ++j)
            bfr[j] = *(const bf16x8*)&Bs[(wn + j * 16 + lm) * 32 + kg * 8];
#pragma unroll
        for (int i = 0; i < 4; ++i)
#pragma unroll
            for (int j = 0; j < 4; ++j)
                acc[i][j] = __builtin_amdgcn_mfma_f32_16x16x32_bf16(af[i], bfr[j], acc[i][j], 0, 0, 0);
        __syncthreads();
    }

#pragma unroll
    for (int j = 0; j < 4; ++j) {
        int col = bn + wn + j * 16 + lm;
        float bv = bias[col];
#pragma unroll
        for (int i = 0; i < 4; ++i) {
            int row0 = bm + wm + i * 16 + kg * 4;
#pragma unroll
            for (int r = 0; r < 4; ++r)
                C[(size_t)(row0 + r) * 768 + col] = f2b(acc[i][j][r] + bv);
        }
    }
}

// ---------------- message pass: one wave per dst node (CSR gather) ----------------
__global__ __launch_bounds__(256) void k_msg(
    const u16* __restrict__ xhb, const u16* __restrict__ rbfh,
    const u16* __restrict__ vinb, const int* __restrict__ srcp,
    const float4* __restrict__ evp, const int* __restrict__ row_ptr,
    float* __restrict__ dx, float* __restrict__ dvec, int base) {
    int d = blockIdx.x * 4 + (threadIdx.x >> 6);
    int lane = threadIdx.x & 63;
    int r0 = row_ptr[d], r1 = row_ptr[d + 1];
    int e0 = r0 > base ? r0 : base;
    int e1 = r1 < base + ECH ? r1 : base + ECH;
    if (e0 >= e1) return;
    float accx[4] = {};
    float accv[3][4] = {};
    for (int j = e0; j < e1; ++j) {
        int s = srcp[j];
        float4 ev4 = evp[j];
        const ushort4* xr = (const ushort4*)(xhb + (size_t)s * 768);
        const ushort4* rr = (const ushort4*)(rbfh + (size_t)(j - base) * 768);
        const ushort4* vr = (const ushort4*)(vinb + (size_t)s * 768);
        U4 X0, X1, X2, Rr0, Rr1, Rr2, V0, V1, V2;
        X0.v = xr[lane]; X1.v = xr[lane + 64]; X2.v = xr[lane + 128];
        Rr0.v = rr[lane]; Rr1.v = rr[lane + 64]; Rr2.v = rr[lane + 128];
        V0.v = vr[lane]; V1.v = vr[lane + 64]; V2.v = vr[lane + 128];
#pragma unroll
        for (int c = 0; c < 4; ++c) {
            float m0 = b2f(X0.a[c]) * b2f(Rr0.a[c]);
            float m1 = b2f(X1.a[c]) * b2f(Rr1.a[c]) * kInvSqrt3;
            float m2 = b2f(X2.a[c]) * b2f(Rr2.a[c]);
            accx[c] += m0;
            accv[0][c] += b2f(V0.a[c]) * m1 + m2 * ev4.x;
            accv[1][c] += b2f(V1.a[c]) * m1 + m2 * ev4.y;
            accv[2][c] += b2f(V2.a[c]) * m1 + m2 * ev4.z;
        }
    }
#pragma unroll
    for (int k = 0; k < 3; ++k)
#pragma unroll
        for (int c = 0; c < 4; ++c) accv[k][c] *= kInvSqrtH;
    bool interior = (r0 >= base) && (r1 <= base + ECH);
    float* pdx = &dx[(size_t)d * 256 + lane * 4];
    float* pv = &dvec[(size_t)d * 768];
    if (interior) {
        *(float4*)pdx = make_float4(accx[0], accx[1], accx[2], accx[3]);
#pragma unroll
        for (int k = 0; k < 3; ++k)
            *(float4*)&pv[k * 256 + lane * 4] =
                make_float4(accv[k][0], accv[k][1], accv[k][2], accv[k][3]);
    } else {
#pragma unroll
        for (int c = 0; c < 4; ++c) {
            atomicAdd(pdx + c, accx[c]);
#pragma unroll
            for (int k = 0; k < 3; ++k)
                atomicAdd(&pv[k * 256 + lane * 4 + c], accv[k][c]);
        }
    }
}

// ---------------- post-message: x=(x+dx)/sqrt2 ; vout=vin+dvec (+bf16) ------------
// block = one node (256 threads)
__global__ void k_post_msg(float* __restrict__ x, const float* __restrict__ dx,
                           const float* __restrict__ vin, const float* __restrict__ dvec,
                           float* __restrict__ vout, u16* __restrict__ vb) {
    int n = blockIdx.x, t = threadIdx.x;
    size_t i = (size_t)n * 256 + t;
    x[i] = (x[i] + dx[i]) * kInvSqrt2;
#pragma unroll
    for (int k = 0; k < 3; ++k) {
        size_t idx = (size_t)n * 768 + k * 256 + t;
        float o = vin[idx] + dvec[idx];
        vout[idx] = o;
        vb[idx] = f2b(o);
    }
}

// ---------------- vec_dot + hcat(bf16) = [x, vnorm]; vp in bf16 -------------------
__global__ void k_vecdot(const u16* __restrict__ vp, const float* __restrict__ x,
                         float* __restrict__ vec_dot, u16* __restrict__ hcat) {
    int i = blockIdx.x * 256 + threadIdx.x;  // N*H
    int n = i >> 8, c = i & 255;
    const u16* p = vp + (size_t)n * 1536;
    float dsum = 0.f, qsum = 0.f;
#pragma unroll
    for (int k = 0; k < 3; ++k) {
        float v1 = b2f(p[k * 512 + c]);
        float v2 = b2f(p[k * 512 + 256 + c]);
        dsum += v1 * v2;
        qsum += v2 * v2;
    }
    vec_dot[i] = dsum * kInvSqrtH;
    hcat[(size_t)n * 512 + c] = f2b(x[i]);
    hcat[(size_t)n * 512 + 256 + c] = f2b(sqrtf(qsum + 1e-8f));
}

// ---------------- update epilogue + fused LayerNorm for next layer ----------------
// block = one node. lnw==null -> emit plain bf16(x) (for energy head).
__global__ void k_update_out(const u16* __restrict__ hout, const float* __restrict__ vec_dot,
                             const u16* __restrict__ vp, float* __restrict__ x,
                             float* __restrict__ vout, u16* __restrict__ vb,
                             const float* __restrict__ lnw, const float* __restrict__ lnb,
                             u16* __restrict__ xout) {
    int n = blockIdx.x, t = threadIdx.x;
    size_t i = (size_t)n * 256 + t;
    float xv1 = b2f(hout[(size_t)n * 768 + t]);
    float xv2 = b2f(hout[(size_t)n * 768 + 256 + t]);
    float xv3 = b2f(hout[(size_t)n * 768 + 512 + t]);
    float dxv = (xv1 + xv2 * vec_dot[i]) * kInvSqrt2;
    float nx = (x[i] + dxv) * kInvSqrt2;
    x[i] = nx;
#pragma unroll
    for (int k = 0; k < 3; ++k) {
        size_t idx = (size_t)n * 768 + k * 256 + t;
        float nv = vout[idx] + xv3 * b2f(vp[(size_t)n * 1536 + k * 512 + t]);
        vout[idx] = nv;
        vb[idx] = f2b(nv);
    }
    if (lnw) {
        float s = nx, q = nx * nx;
#pragma unroll
        for (int m = 32; m >= 1; m >>= 1) {
            s += __shfl_xor(s, m, 64);
            q += __shfl_xor(q, m, 64);
        }
        __shared__ float s_sum[4], s_sq[4];
        int wid = t >> 6;
        if ((t & 63) == 0) { s_sum[wid] = s; s_sq[wid] = q; }
        __syncthreads();
        float S = s_sum[0] + s_sum[1] + s_sum[2] + s_sum[3];
        float Q = s_sq[0] + s_sq[1] + s_sq[2] + s_sq[3];
        float mu = S * (1.0f / HH);
        float var = Q * (1.0f / HH) - mu * mu;
        float rs = rsqrtf(var + 1e-5f);
        xout[i] = f2b((nx - mu) * rs * lnw[t] + lnb[t]);
    } else {
        xout[i] = f2b(nx);
    }
}

// ---------------- energy reduce: LDS segment sum (batch sorted), few atomics -------
__global__ void k_energy2(const float* __restrict__ h, const float* __restrict__ w2,
                          const float* __restrict__ b2, const int* __restrict__ batch,
                          float* __restrict__ out) {
    __shared__ float g[NGG];
    int t = threadIdx.x;
    if (t < NGG) g[t] = 0.f;
    __syncthreads();
    int a = blockIdx.x * 256 + t;             // 32 blocks x 256 threads = 8192 atoms
    const float4* hr = (const float4*)(h + (size_t)a * 128);
    const float4* w4 = (const float4*)w2;
    float acc = 0.f;
#pragma unroll 8
    for (int i = 0; i < 32; ++i) {
        float4 hv = hr[i], wv = w4[i];
        acc += hv.x * wv.x + hv.y * wv.y + hv.z * wv.z + hv.w * wv.w;
    }
    acc += b2[0];
    atomicAdd(&g[batch[a]], acc);
    __syncthreads();
    if (t < NGG && g[t] != 0.f) atomicAdd(&out[t], g[t]);
}

extern "C" void kernel_launch(void* const* d_in, const int* in_sizes, int n_in,
                              void* d_out, int out_size, void* d_ws, size_t ws_size,
                              hipStream_t stream) {
    const float* pos      = (const float*)d_in[0];
    const float* atom_emb = (const float*)d_in[1];
    const float* ln_w     = (const float*)d_in[2];
    const float* ln_b     = (const float*)d_in[3];
    const float* xp_w1    = (const float*)d_in[4];
    const float* xp_b1    = (const float*)d_in[5];
    const float* xp_w2    = (const float*)d_in[6];
    const float* xp_b2    = (const float*)d_in[7];
    const float* rbf_w    = (const float*)d_in[8];
    const float* rbf_b    = (const float*)d_in[9];
    const float* vec_w    = (const float*)d_in[10];
    const float* xv_w1    = (const float*)d_in[11];
    const float* xv_b1    = (const float*)d_in[12];
    const float* xv_w2    = (const float*)d_in[13];
    const float* xv_b2    = (const float*)d_in[14];
    const float* oe_w1    = (const float*)d_in[15];
    const float* oe_b1    = (const float*)d_in[16];
    const float* oe_w2    = (const float*)d_in[17];
    const float* oe_b2    = (const float*)d_in[18];
    const int*   z        = (const int*)d_in[19];
    const int*   ei       = (const int*)d_in[20];
    const int*   batch    = (const int*)d_in[21];
    float* out = (float*)d_out;

    // ---- workspace plan (~234 MB of 256 MiB; aliased live ranges) ----
    char* ws = (char*)d_ws;
    size_t off = 0;
    auto alloc = [&](size_t b) {
        void* p = ws + off;
        off = (off + b + 255) & ~(size_t)255;
        return p;
    };
    float*  x      = (float*)alloc((size_t)NN * HH * 4);       //   8 MB
    float*  vecA   = (float*)alloc((size_t)NN * 768 * 4);      //  24 MB  \ adjacent:
    u16*    vb     = (u16*)alloc((size_t)NN * 768 * 2);        //  12 MB  / joint zero
    float*  vecB   = (float*)alloc((size_t)NN * 768 * 4);      //  24 MB
    float*  dx     = (float*)alloc((size_t)NN * HH * 4);       //   8 MB  \ adjacent:
    float*  dvec   = (float*)alloc((size_t)NN * 768 * 4);      //  24 MB  / joint zero
    u16*    xlnb   = (u16*)alloc((size_t)NN * HH * 2);         //   4 MB
    u16*    t1b    = (u16*)alloc((size_t)NN * HH * 2);         //   4 MB (alias h1b)
    u16*    xhb    = (u16*)alloc((size_t)NN * 768 * 2);        //  12 MB (alias hcatb)
    float*  vdot   = (float*)alloc((size_t)NN * HH * 4);       //   8 MB (alias heng)
    char*   big    = (char*)alloc((size_t)ECH * 768 * 2);      //  96 MB (rbfhc | vpb+houtb)
    float*  ev     = (float*)alloc((size_t)EE * 4 * 4);        //   2 MB
    // CSR
    int*    deg    = (int*)alloc((size_t)NN * 4);
    int*    row_ptr= (int*)alloc((size_t)(NN + 1) * 4);
    int*    fill   = (int*)alloc((size_t)NN * 4);
    int*    srcp   = (int*)alloc((size_t)EE * 4);
    float4* evp    = (float4*)alloc((size_t)EE * 16);          //   2 MB
    // transposed bf16 weights (~5 MB)
    u16* xp_w1T = (u16*)alloc((size_t)3 * 256 * 256 * 2);
    u16* xp_w2T = (u16*)alloc((size_t)3 * 768 * 256 * 2);
    u16* rbf_wT = (u16*)alloc((size_t)3 * 768 * 128 * 2);
    u16* vec_wT = (u16*)alloc((size_t)3 * 512 * 256 * 2);
    u16* xv_w1T = (u16*)alloc((size_t)3 * 256 * 512 * 2);
    u16* xv_w2T = (u16*)alloc((size_t)3 * 768 * 256 * 2);
    u16* oe_w1T = (u16*)alloc((size_t)128 * 256 * 2);
    (void)ws_size;

    u16*   rbfhc = (u16*)big;                       // [ECH,768] bf16, message phase
    u16*   vpb   = (u16*)big;                       // [N,1536] bf16, update phase
    u16*   houtb = (u16*)(big + (size_t)NN * 1536 * 2); // [N,768] bf16, update phase
    u16*   h1b   = t1b;
    u16*   hcatb = xhb;
    float* heng  = vdot;                            // [N,128] fp32, energy phase
    u16*   xb    = xlnb;

    // ---- setup: weights, init+LN, CSR ----
    k_wt_all<<<2432, 256, 0, stream>>>(xp_w1, xp_w2, rbf_w, vec_w, xv_w1, xv_w2, oe_w1,
                                       xp_w1T, xp_w2T, rbf_wT, vec_wT, xv_w1T, xv_w2T, oe_w1T);
    k_zero<<<(36 * 1024 * 1024 / 16 + 255) / 256, 256, 0, stream>>>(vecA, 36 * 1024 * 1024 / 16);
    k_zero<<<8, 256, 0, stream>>>((float*)deg, NN / 4);
    k_init_ln<<<NN, 256, 0, stream>>>(atom_emb, z, ln_w, ln_b, x, xlnb);
    k_edge_geom<<<EE / 256, 256, 0, stream>>>(pos, ei, ev);
    k_hist<<<EE / 256, 256, 0, stream>>>(ei, deg);
    k_scan<<<1, 256, 0, stream>>>(deg, row_ptr, fill);
    k_scatter<<<EE / 256, 256, 0, stream>>>(ei, ev, fill, srcp, evp);

    float* vin = vecA;
    float* vout = vecB;
    for (int l = 0; l < LL; ++l) {
        // ---- PaiNNMessage ----
        k_gemm<1, 1><<<dim3(2, NN / 128), 256, 0, stream>>>(
            xlnb, xp_w1T + (size_t)l * 256 * 256, xp_b1 + l * HH, t1b, NN, 256, 256);
        k_gemm<1, 0><<<dim3(6, NN / 128), 256, 0, stream>>>(
            t1b, xp_w2T + (size_t)l * 768 * 256, xp_b2 + l * 768, xhb, NN, 256, 768);
        k_zero<<<(32 * 1024 * 1024 / 16 + 255) / 256, 256, 0, stream>>>(dx, 32 * 1024 * 1024 / 16);
        for (int c0 = 0; c0 < NCHUNK; ++c0) {
            int base = c0 * ECH;
            k_rbfgemm<<<dim3(6, ECH / 128), 256, 0, stream>>>(
                evp, rbf_wT + (size_t)l * 768 * 128, rbf_b + l * 768, rbfhc, base);
            k_msg<<<NN / 4, 256, 0, stream>>>(xhb, rbfhc, vb, srcp, evp, row_ptr, dx, dvec, base);
        }
        k_post_msg<<<NN, 256, 0, stream>>>(x, dx, vin, dvec, vout, vb);

        // ---- PaiNNUpdate ----
        k_gemm<1, 0><<<dim3(4, 3 * NN / 128), 256, 0, stream>>>(
            vb, vec_wT + (size_t)l * 512 * 256, nullptr, vpb, 3 * NN, 256, 512);
        k_vecdot<<<NN, 256, 0, stream>>>(vpb, x, vdot, hcatb);
        k_gemm<1, 1><<<dim3(2, NN / 128), 256, 0, stream>>>(
            hcatb, xv_w1T + (size_t)l * 256 * 512, xv_b1 + l * HH, h1b, NN, 512, 256);
        k_gemm<1, 0><<<dim3(6, NN / 128), 256, 0, stream>>>(
            h1b, xv_w2T + (size_t)l * 768 * 256, xv_b2 + l * 768, houtb, NN, 256, 768);
        bool last = (l == LL - 1);
        k_update_out<<<NN, 256, 0, stream>>>(
            houtb, vdot, vpb, x, vout, vb,
            last ? nullptr : ln_w + (l + 1) * HH,
            last ? nullptr : ln_b + (l + 1) * HH, xlnb);

        float* tmp = vin; vin = vout; vout = tmp;
    }

    // ---- energy head ----
    k_gemm<0, 1><<<dim3(1, NN / 128), 256, 0, stream>>>(
        xb, oe_w1T, oe_b1, heng, NN, 256, 128);
    k_zero<<<1, 256, 0, stream>>>(out, NGG / 4);
    k_energy2<<<32, 256, 0, stream>>>(heng, oe_w2, oe_b2, batch, out);
}